// Round 4
// baseline (1198.889 us; speedup 1.0000x reference)
//
#include <hip/hip_runtime.h>
#include <math.h>

#define PI_F 3.14159265358979323846f
#define KS 258   // padded column count of half-spectrum G (k in [0,256], stride 258)

// ---------------------------------------------------------------- FFT core
__device__ __forceinline__ void fft512(float* re, float* im,
                                       const float* twr, const float* twi, int t) {
#pragma unroll
  for (int s = 0; s < 9; ++s) {
    __syncthreads();
    int h  = 1 << s;
    int j  = t & (h - 1);
    int i1 = ((t >> s) << (s + 1)) + j;
    int i2 = i1 + h;
    int ti = j << (8 - s);
    float wr = twr[ti], wi = twi[ti];
    float ur = re[i1], ui = im[i1];
    float vr = re[i2], vi = im[i2];
    float tr = vr * wr - vi * wi;
    float tq = vr * wi + vi * wr;
    re[i1] = ur + tr; im[i1] = ui + tq;
    re[i2] = ur - tr; im[i2] = ui - tq;
  }
}

__device__ __forceinline__ void init_tw(float* twr, float* twi, int t) {
  float s, c;
  sincosf(-2.0f * PI_F * (float)t * (1.0f / 512.0f), &s, &c);
  twr[t] = c; twi[t] = s;
}

// ------------------------------------------------- K1: gray + paired-row FFT (Hermitian pack)
__global__ __launch_bounds__(256) void k_rowfft(const float* __restrict__ x,
                                                float2* __restrict__ G) {
  __shared__ float re[512], im[512], twr[256], twi[256];
  int t = threadIdx.x;
  int q = blockIdx.x;
  int b = blockIdx.y;
  int r0 = 2 * q;
  const float* xb = x + ((size_t)b * 3 * 512 + r0) * 512;
  float a0 = 0.299f * xb[t]           + 0.587f * xb[262144 + t]           + 0.114f * xb[524288 + t];
  float a1 = 0.299f * xb[t + 256]     + 0.587f * xb[262144 + t + 256]     + 0.114f * xb[524288 + t + 256];
  float c0 = 0.299f * xb[512 + t]     + 0.587f * xb[262656 + t]           + 0.114f * xb[524800 + t];
  float c1 = 0.299f * xb[512 + t + 256] + 0.587f * xb[262656 + t + 256]   + 0.114f * xb[524800 + t + 256];
  int rv0 = __brev((unsigned)t) >> 23;
  int rv1 = __brev((unsigned)(t + 256)) >> 23;
  re[rv0] = a0; im[rv0] = c0;
  re[rv1] = a1; im[rv1] = c1;
  init_tw(twr, twi, t);
  fft512(re, im, twr, twi, t);
  __syncthreads();
  float2* G0 = G + ((size_t)b * 512 + r0) * KS;
  float2* G1 = G0 + KS;
  for (int k = t; k <= 256; k += 256) {
    int mk = (512 - k) & 511;
    float zr = re[k], zi = im[k];
    float mr = re[mk], mi = im[mk];
    G0[k] = make_float2(0.5f * (zr + mr), 0.5f * (zi - mi));
    G1[k] = make_float2(0.5f * (zi + mi), 0.5f * (mr - zr));
  }
}

// ------------------------------------------------- K1.5: out-of-place transpose G -> GT
__global__ __launch_bounds__(256) void k_transpose(const float2* __restrict__ G,
                                                   float2* __restrict__ GT) {
  __shared__ float2 ta[32][33];
  int kt = blockIdx.x, rt = blockIdx.y, b = blockIdx.z;
  int tx = threadIdx.x, ty = threadIdx.y;
  int k0 = kt * 32, r0 = rt * 32;
  const float2* Gb = G + (size_t)b * 512 * KS;
  float2* GTb = GT + (size_t)b * KS * 512;
#pragma unroll
  for (int i = 0; i < 32; i += 8) {
    int k = k0 + tx;
    float2 v = make_float2(0.0f, 0.0f);
    if (k < KS) v = Gb[(size_t)(r0 + ty + i) * KS + k];
    ta[ty + i][tx] = v;
  }
  __syncthreads();
#pragma unroll
  for (int i = 0; i < 32; i += 8) {
    int k = k0 + ty + i;
    if (k < KS) GTb[(size_t)k * 512 + r0 + tx] = ta[tx][ty + i];
  }
}

// ------------------------------------------------- K2: column FFT + mag/log1p/fftshift + mirror + stats
__global__ __launch_bounds__(256) void k_colfft(const float2* __restrict__ GT,
                                                float* __restrict__ S,
                                                double* __restrict__ stats) {
  __shared__ float re[512], im[512], twr[256], twi[256];
  int t  = threadIdx.x;
  int kc = blockIdx.x;
  int b  = blockIdx.y;
  const float2* Gc = GT + ((size_t)b * KS + kc) * 512;
  float2 v0 = Gc[t], v1 = Gc[t + 256];
  int rv0 = __brev((unsigned)t) >> 23;
  int rv1 = __brev((unsigned)(t + 256)) >> 23;
  re[rv0] = v0.x; im[rv0] = v0.y;
  re[rv1] = v1.x; im[rv1] = v1.y;
  init_tw(twr, twi, t);
  fft512(re, im, twr, twi, t);
  float m0 = log1pf(sqrtf(re[t] * re[t] + im[t] * im[t]));
  float m1 = log1pf(sqrtf(re[t + 256] * re[t + 256] + im[t + 256] * im[t + 256]));
  int v = (kc + 256) & 511;
  float* Sb = S + (size_t)b * 262144;
  Sb[(size_t)v * 512 + t + 256] = m0;
  Sb[(size_t)v * 512 + t]       = m1;
  bool mir = (kc >= 1) && (kc <= 255);
  if (mir) {
    int vp = 256 - kc;
    Sb[(size_t)vp * 512 + ((256 - t) & 511)] = m0;
    Sb[(size_t)vp * 512 + ((512 - t) & 511)] = m1;
  }
  __syncthreads();
  re[t] = m0 + m1;
  im[t] = m0 * m0 + m1 * m1;
  __syncthreads();
  for (int s = 128; s > 0; s >>= 1) {
    if (t < s) { re[t] += re[t + s]; im[t] += im[t + s]; }
    __syncthreads();
  }
  if (t == 0) {
    double wgt = mir ? 2.0 : 1.0;
    atomicAdd(&stats[2 * b],     wgt * (double)re[0]);
    atomicAdd(&stats[2 * b + 1], wgt * (double)im[0]);
  }
}

__global__ void k_zero_stats(double* stats) {
  stats[threadIdx.x] = 0.0;
}

__global__ void k_stats(const double* __restrict__ stats, float2* __restrict__ muinv) {
  int i = threadIdx.x;  // 64
  double n  = 262144.0;
  double mu = stats[2 * i] / n;
  double va = stats[2 * i + 1] / n - mu * mu;
  if (va < 0.0) va = 0.0;
  double sd = sqrt(va);
  muinv[i] = make_float2((float)mu, (float)(1.0 / (sd + 1e-8)));
}

// ------------------------------------------------- K4: conv1(5x5,s2,p2) + BN + ReLU + maxpool2
#define TS1 68
__global__ __launch_bounds__(256) void k_conv1(
    const float* __restrict__ S, const float2* __restrict__ muinv,
    const float* __restrict__ w, const float* __restrict__ cb,
    const float* __restrict__ g, const float* __restrict__ bb,
    const float* __restrict__ bm, const float* __restrict__ bv,
    float* __restrict__ h1) {
  __shared__ float tile[67 * TS1];
  int b = blockIdx.y;
  int by = blockIdx.x >> 3, bx = blockIdx.x & 7;
  int y0 = by * 16, x0 = bx * 16;
  int h0 = 4 * y0 - 2, w0 = 4 * x0 - 2;
  float2 mi = muinv[b];
  const float* Sb = S + (size_t)b * 262144;
  for (int idx = threadIdx.x; idx < 67 * 67; idx += 256) {
    int wl = idx / 67, hl = idx - wl * 67;
    int hh = h0 + hl, ww = w0 + wl;
    float val = 0.0f;
    if (hh >= 0 && hh < 512 && ww >= 0 && ww < 512)
      val = (Sb[(size_t)ww * 512 + hh] - mi.x) * mi.y;
    tile[wl * TS1 + hl] = val;
  }
  __syncthreads();
  int ty = threadIdx.x >> 4, tx = threadIdx.x & 15;
  float in[7][7];
#pragma unroll
  for (int j = 0; j < 7; ++j)
#pragma unroll
    for (int i = 0; i < 7; ++i)
      in[i][j] = tile[(4 * tx + j) * TS1 + 4 * ty + i];
  int Y = y0 + ty, X = x0 + tx;
  for (int occ = 0; occ < 8; ++occ) {
    float w4[4][25];
#pragma unroll
    for (int jo = 0; jo < 4; ++jo)
#pragma unroll
      for (int k = 0; k < 25; ++k)
        w4[jo][k] = w[(occ * 4 + jo) * 25 + k];
#pragma unroll
    for (int jo = 0; jo < 4; ++jo) {
      int oc = occ * 4 + jo;
      float a00 = 0.f, a01 = 0.f, a10 = 0.f, a11 = 0.f;
#pragma unroll
      for (int dy = 0; dy < 5; ++dy)
#pragma unroll
        for (int dx = 0; dx < 5; ++dx) {
          float wv = w4[jo][dy * 5 + dx];
          a00 = fmaf(wv, in[dy][dx], a00);
          a01 = fmaf(wv, in[dy][dx + 2], a01);
          a10 = fmaf(wv, in[dy + 2][dx], a10);
          a11 = fmaf(wv, in[dy + 2][dx + 2], a11);
        }
      float m   = fmaxf(fmaxf(a00, a01), fmaxf(a10, a11));
      float inv = g[oc] / sqrtf(bv[oc] + 1e-5f);
      float sh  = cb[oc] * inv + bb[oc] - bm[oc] * inv;
      h1[(((size_t)b * 32 + oc) * 128 + Y) * 128 + X] = fmaxf(m * inv + sh, 0.0f);
    }
  }
}

// ------------------------------------------------- K5: conv2(3x3,s2,p1,32->64) + BN + ReLU + maxpool2
// v4: 256 threads / 4 waves, EACH WAVE computes 16 oc (all 64 oc per block).
// Same LDS staging as v3 (once per tile), but ds_read instructions per FMA halve:
// one in[5][5] patch (10 x b128) now feeds 16 oc x 9 = 144 FMAs.
// Default launch_bounds: compiler free to take ~128 VGPR (round-2 spill was the
// forced 64-VGPR budget, not the 16-oc shape). TS2 40 to perturb 4-way conflicts.
#define TS2 40
__global__ __launch_bounds__(256) void k_conv2(
    const float* __restrict__ h1, const float* __restrict__ w,
    const float* __restrict__ cb, const float* __restrict__ g,
    const float* __restrict__ bb, const float* __restrict__ bm,
    const float* __restrict__ bv, float* __restrict__ h2) {
  __shared__ __attribute__((aligned(16))) float tile[8 * 33 * TS2];  // 42240 B
  int tid = threadIdx.x;
  int b = blockIdx.y;
  int rt = blockIdx.x >> 2, ct = blockIdx.x & 3;
  int ty0 = rt * 16, tx0 = ct * 16;                     // conv-tile origin (16x16 conv)
  int wv = tid >> 6;                                    // wave id 0..3 -> 16-oc subgroup
  int lane = tid & 63;
  int qy = lane >> 3, qx = lane & 7;                    // 8x8 quads = 8x8 pooled outputs
  int iy0 = 2 * ty0 - 1, ix0 = 2 * tx0 - 1;
  int ocbase = wv * 16;
  float acc[16][4];
#pragma unroll
  for (int q = 0; q < 16; ++q)
#pragma unroll
    for (int p = 0; p < 4; ++p) acc[q][p] = 0.0f;

  for (int ict = 0; ict < 4; ++ict) {
    __syncthreads();
    for (int idx = tid; idx < 8 * 33 * 33; idx += 256) {
      int ic = idx / 1089;
      int rem = idx - ic * 1089;
      int rr = rem / 33, cc = rem - rr * 33;
      int iy = iy0 + rr, ix = ix0 + cc;
      float v = 0.0f;
      int icg = ict * 8 + ic;
      if (iy >= 0 && iy < 128 && ix >= 0 && ix < 128)
        v = h1[(((size_t)b * 32 + icg) * 128 + iy) * 128 + ix];
      tile[(ic * 33 + rr) * TS2 + cc] = v;
    }
    __syncthreads();
    int rbase = 4 * qy, cbase = 4 * qx;
#pragma unroll
    for (int ic = 0; ic < 8; ++ic) {
      int icg = ict * 8 + ic;
      float in[5][5];
#pragma unroll
      for (int i = 0; i < 5; ++i) {
        int base = (ic * 33 + rbase + i) * TS2 + cbase;
        float4 a  = *reinterpret_cast<const float4*>(&tile[base]);
        float4 bq = *reinterpret_cast<const float4*>(&tile[base + 4]);
        in[i][0] = a.x; in[i][1] = a.y; in[i][2] = a.z; in[i][3] = a.w;
        in[i][4] = bq.x;
      }
      const float* wic = w + ((size_t)ocbase * 32 + icg) * 9;
#pragma unroll
      for (int q = 0; q < 16; ++q) {
        const float* wo = wic + (size_t)q * 32 * 9;
#pragma unroll
        for (int dy = 0; dy < 3; ++dy)
#pragma unroll
          for (int dx = 0; dx < 3; ++dx) {
            float wvv = wo[dy * 3 + dx];
            acc[q][0] = fmaf(wvv, in[dy][dx],         acc[q][0]);
            acc[q][1] = fmaf(wvv, in[dy][dx + 2],     acc[q][1]);
            acc[q][2] = fmaf(wvv, in[dy + 2][dx],     acc[q][2]);
            acc[q][3] = fmaf(wvv, in[dy + 2][dx + 2], acc[q][3]);
          }
      }
    }
  }
  int Yp = (ty0 >> 1) + qy, Xp = (tx0 >> 1) + qx;
#pragma unroll
  for (int q = 0; q < 16; ++q) {
    int oc = ocbase + q;
    float m   = fmaxf(fmaxf(acc[q][0], acc[q][1]), fmaxf(acc[q][2], acc[q][3]));
    float inv = g[oc] / sqrtf(bv[oc] + 1e-5f);
    float sh  = cb[oc] * inv + bb[oc] - bm[oc] * inv;
    h2[(((size_t)b * 64 + oc) * 32 + Yp) * 32 + Xp] = fmaxf(m * inv + sh, 0.0f);
  }
}

// ------------------------------------------------- K6: conv3(3x3,s2,p1,64->128) + BN + ReLU + GAP
#define TS3 34
__global__ __launch_bounds__(256) void k_conv3(
    const float* __restrict__ h2, const float* __restrict__ w,
    const float* __restrict__ cb, const float* __restrict__ g,
    const float* __restrict__ bb, const float* __restrict__ bm,
    const float* __restrict__ bv, float* __restrict__ gap) {
  __shared__ __attribute__((aligned(16))) float tile[8 * 33 * TS3];
  __shared__ float red[256];
  int tid = threadIdx.x;
  int ocg = blockIdx.x, b = blockIdx.y;
  int cy = tid >> 4, cx = tid & 15;
  float acc[8];
#pragma unroll
  for (int q = 0; q < 8; ++q) acc[q] = 0.0f;

  for (int ict = 0; ict < 8; ++ict) {
    __syncthreads();
    for (int idx = tid; idx < 8 * 33 * 33; idx += 256) {
      int ic = idx / 1089;
      int rem = idx - ic * 1089;
      int rr = rem / 33, cc = rem - rr * 33;
      int iy = rr - 1, ix = cc - 1;
      float v = 0.0f;
      int icg = ict * 8 + ic;
      if (iy >= 0 && iy < 32 && ix >= 0 && ix < 32)
        v = h2[(((size_t)b * 64 + icg) * 32 + iy) * 32 + ix];
      tile[(ic * 33 + rr) * TS3 + cc] = v;
    }
    __syncthreads();
#pragma unroll
    for (int ic = 0; ic < 8; ++ic) {
      int icg = ict * 8 + ic;
      float in[3][3];
#pragma unroll
      for (int i = 0; i < 3; ++i) {
        const float2* r2 = reinterpret_cast<const float2*>(&tile[(ic * 33 + 2 * cy + i) * TS3 + 2 * cx]);
        float2 a = r2[0];
        in[i][0] = a.x; in[i][1] = a.y;
        in[i][2] = tile[(ic * 33 + 2 * cy + i) * TS3 + 2 * cx + 2];
      }
      const float* wic = w + ((size_t)(ocg * 8) * 64 + icg) * 9;
#pragma unroll
      for (int q = 0; q < 8; ++q) {
        const float* wo = wic + (size_t)q * 64 * 9;
#pragma unroll
        for (int i = 0; i < 3; ++i)
#pragma unroll
          for (int j = 0; j < 3; ++j)
            acc[q] = fmaf(wo[i * 3 + j], in[i][j], acc[q]);
      }
    }
  }
  for (int q = 0; q < 8; ++q) {
    int oc = ocg * 8 + q;
    float inv = g[oc] / sqrtf(bv[oc] + 1e-5f);
    float sh  = cb[oc] * inv + bb[oc] - bm[oc] * inv;
    float val = fmaxf(acc[q] * inv + sh, 0.0f);
    __syncthreads();
    red[tid] = val;
    __syncthreads();
    for (int s = 128; s > 0; s >>= 1) {
      if (tid < s) red[tid] += red[tid + s];
      __syncthreads();
    }
    if (tid == 0) gap[(size_t)b * 128 + oc] = red[0] * (1.0f / 256.0f);
  }
}

// ------------------------------------------------- K7: FC1+ReLU+FC2+ReLU
__global__ __launch_bounds__(256) void k_fc(
    const float* __restrict__ gap,
    const float* __restrict__ w1, const float* __restrict__ b1,
    const float* __restrict__ w2, const float* __restrict__ b2,
    float* __restrict__ out) {
  __shared__ float gv[128], hv[256];
  int b = blockIdx.x, t = threadIdx.x;
  if (t < 128) gv[t] = gap[(size_t)b * 128 + t];
  __syncthreads();
  float a1 = b1[t];
  const float* wr = w1 + (size_t)t * 128;
  for (int k = 0; k < 128; ++k) a1 = fmaf(wr[k], gv[k], a1);
  hv[t] = fmaxf(a1, 0.0f);
  __syncthreads();
  if (t < 128) {
    float a2 = b2[t];
    const float* wr2 = w2 + (size_t)t * 256;
    for (int k = 0; k < 256; ++k) a2 = fmaf(wr2[k], hv[k], a2);
    out[(size_t)b * 128 + t] = fmaxf(a2, 0.0f);
  }
}

// ================================================================ launch
extern "C" void kernel_launch(void* const* d_in, const int* in_sizes, int n_in,
                              void* d_out, int out_size, void* d_ws, size_t ws_size,
                              hipStream_t stream) {
  (void)in_sizes; (void)n_in; (void)out_size; (void)ws_size;
  const float* x   = (const float*)d_in[0];
  const float* c1w = (const float*)d_in[1];
  const float* c1b = (const float*)d_in[2];
  const float* b1g = (const float*)d_in[3];
  const float* b1b = (const float*)d_in[4];
  const float* b1m = (const float*)d_in[5];
  const float* b1v = (const float*)d_in[6];
  const float* c2w = (const float*)d_in[7];
  const float* c2b = (const float*)d_in[8];
  const float* b2g = (const float*)d_in[9];
  const float* b2b = (const float*)d_in[10];
  const float* b2m = (const float*)d_in[11];
  const float* b2v = (const float*)d_in[12];
  const float* c3w = (const float*)d_in[13];
  const float* c3b = (const float*)d_in[14];
  const float* b3g = (const float*)d_in[15];
  const float* b3b = (const float*)d_in[16];
  const float* b3m = (const float*)d_in[17];
  const float* b3v = (const float*)d_in[18];
  const float* f1w = (const float*)d_in[19];
  const float* f1b = (const float*)d_in[20];
  const float* f2w = (const float*)d_in[21];
  const float* f2b = (const float*)d_in[22];
  float* out = (float*)d_out;

  char* ws = (char*)d_ws;
  float2* G     = (float2*)(ws + 0);
  float2* GT    = (float2*)(ws + 67633152ull);
  float*  S     = (float*) (ws + 135266304ull);
  double* stats = (double*)(ws + 202375168ull);
  float2* muinv = (float2*)(ws + 202376192ull);
  float*  gap   = (float*) (ws + 202376704ull);
  float*  h1    = (float*) (ws + 0);
  float*  h2    = (float*) (ws + 135266304ull);

  k_zero_stats<<<1, 128, 0, stream>>>(stats);
  k_rowfft   <<<dim3(256, 64), 256, 0, stream>>>(x, G);
  k_transpose<<<dim3(9, 16, 64), dim3(32, 8), 0, stream>>>(G, GT);
  k_colfft   <<<dim3(257, 64), 256, 0, stream>>>(GT, S, stats);
  k_stats    <<<1, 64, 0, stream>>>(stats, muinv);
  k_conv1    <<<dim3(64, 64), 256, 0, stream>>>(S, muinv, c1w, c1b, b1g, b1b, b1m, b1v, h1);
  k_conv2    <<<dim3(16, 64), 256, 0, stream>>>(h1, c2w, c2b, b2g, b2b, b2m, b2v, h2);
  k_conv3    <<<dim3(16, 64), 256, 0, stream>>>(h2, c3w, c3b, b3g, b3b, b3m, b3v, gap);
  k_fc       <<<64, 256, 0, stream>>>(gap, f1w, f1b, f2w, f2b, out);
}

// Round 5
// 1025.936 us; speedup vs baseline: 1.1686x; 1.1686x over previous
//
#include <hip/hip_runtime.h>
#include <math.h>

#define PI_F 3.14159265358979323846f
#define KS 258   // padded column count of half-spectrum G (k in [0,256], stride 258)

// ---------------------------------------------------------------- FFT core
__device__ __forceinline__ void fft512(float* re, float* im,
                                       const float* twr, const float* twi, int t) {
#pragma unroll
  for (int s = 0; s < 9; ++s) {
    __syncthreads();
    int h  = 1 << s;
    int j  = t & (h - 1);
    int i1 = ((t >> s) << (s + 1)) + j;
    int i2 = i1 + h;
    int ti = j << (8 - s);
    float wr = twr[ti], wi = twi[ti];
    float ur = re[i1], ui = im[i1];
    float vr = re[i2], vi = im[i2];
    float tr = vr * wr - vi * wi;
    float tq = vr * wi + vi * wr;
    re[i1] = ur + tr; im[i1] = ui + tq;
    re[i2] = ur - tr; im[i2] = ui - tq;
  }
}

__device__ __forceinline__ void init_tw(float* twr, float* twi, int t) {
  float s, c;
  sincosf(-2.0f * PI_F * (float)t * (1.0f / 512.0f), &s, &c);
  twr[t] = c; twi[t] = s;
}

// ------------------------------------------------- K1: gray + paired-row FFT (Hermitian pack)
__global__ __launch_bounds__(256) void k_rowfft(const float* __restrict__ x,
                                                float2* __restrict__ G) {
  __shared__ float re[512], im[512], twr[256], twi[256];
  int t = threadIdx.x;
  int q = blockIdx.x;
  int b = blockIdx.y;
  int r0 = 2 * q;
  const float* xb = x + ((size_t)b * 3 * 512 + r0) * 512;
  float a0 = 0.299f * xb[t]           + 0.587f * xb[262144 + t]           + 0.114f * xb[524288 + t];
  float a1 = 0.299f * xb[t + 256]     + 0.587f * xb[262144 + t + 256]     + 0.114f * xb[524288 + t + 256];
  float c0 = 0.299f * xb[512 + t]     + 0.587f * xb[262656 + t]           + 0.114f * xb[524800 + t];
  float c1 = 0.299f * xb[512 + t + 256] + 0.587f * xb[262656 + t + 256]   + 0.114f * xb[524800 + t + 256];
  int rv0 = __brev((unsigned)t) >> 23;
  int rv1 = __brev((unsigned)(t + 256)) >> 23;
  re[rv0] = a0; im[rv0] = c0;
  re[rv1] = a1; im[rv1] = c1;
  init_tw(twr, twi, t);
  fft512(re, im, twr, twi, t);
  __syncthreads();
  float2* G0 = G + ((size_t)b * 512 + r0) * KS;
  float2* G1 = G0 + KS;
  for (int k = t; k <= 256; k += 256) {
    int mk = (512 - k) & 511;
    float zr = re[k], zi = im[k];
    float mr = re[mk], mi = im[mk];
    G0[k] = make_float2(0.5f * (zr + mr), 0.5f * (zi - mi));
    G1[k] = make_float2(0.5f * (zi + mi), 0.5f * (mr - zr));
  }
}

// ------------------------------------------------- K1.5: out-of-place transpose G -> GT
__global__ __launch_bounds__(256) void k_transpose(const float2* __restrict__ G,
                                                   float2* __restrict__ GT) {
  __shared__ float2 ta[32][33];
  int kt = blockIdx.x, rt = blockIdx.y, b = blockIdx.z;
  int tx = threadIdx.x, ty = threadIdx.y;
  int k0 = kt * 32, r0 = rt * 32;
  const float2* Gb = G + (size_t)b * 512 * KS;
  float2* GTb = GT + (size_t)b * KS * 512;
#pragma unroll
  for (int i = 0; i < 32; i += 8) {
    int k = k0 + tx;
    float2 v = make_float2(0.0f, 0.0f);
    if (k < KS) v = Gb[(size_t)(r0 + ty + i) * KS + k];
    ta[ty + i][tx] = v;
  }
  __syncthreads();
#pragma unroll
  for (int i = 0; i < 32; i += 8) {
    int k = k0 + ty + i;
    if (k < KS) GTb[(size_t)k * 512 + r0 + tx] = ta[tx][ty + i];
  }
}

// ------------------------------------------------- K2: column FFT + mag/log1p/fftshift + mirror + stats
__global__ __launch_bounds__(256) void k_colfft(const float2* __restrict__ GT,
                                                float* __restrict__ S,
                                                double* __restrict__ stats) {
  __shared__ float re[512], im[512], twr[256], twi[256];
  int t  = threadIdx.x;
  int kc = blockIdx.x;
  int b  = blockIdx.y;
  const float2* Gc = GT + ((size_t)b * KS + kc) * 512;
  float2 v0 = Gc[t], v1 = Gc[t + 256];
  int rv0 = __brev((unsigned)t) >> 23;
  int rv1 = __brev((unsigned)(t + 256)) >> 23;
  re[rv0] = v0.x; im[rv0] = v0.y;
  re[rv1] = v1.x; im[rv1] = v1.y;
  init_tw(twr, twi, t);
  fft512(re, im, twr, twi, t);
  float m0 = log1pf(sqrtf(re[t] * re[t] + im[t] * im[t]));
  float m1 = log1pf(sqrtf(re[t + 256] * re[t + 256] + im[t + 256] * im[t + 256]));
  int v = (kc + 256) & 511;
  float* Sb = S + (size_t)b * 262144;
  Sb[(size_t)v * 512 + t + 256] = m0;
  Sb[(size_t)v * 512 + t]       = m1;
  bool mir = (kc >= 1) && (kc <= 255);
  if (mir) {
    int vp = 256 - kc;
    Sb[(size_t)vp * 512 + ((256 - t) & 511)] = m0;
    Sb[(size_t)vp * 512 + ((512 - t) & 511)] = m1;
  }
  __syncthreads();
  re[t] = m0 + m1;
  im[t] = m0 * m0 + m1 * m1;
  __syncthreads();
  for (int s = 128; s > 0; s >>= 1) {
    if (t < s) { re[t] += re[t + s]; im[t] += im[t + s]; }
    __syncthreads();
  }
  if (t == 0) {
    double wgt = mir ? 2.0 : 1.0;
    atomicAdd(&stats[2 * b],     wgt * (double)re[0]);
    atomicAdd(&stats[2 * b + 1], wgt * (double)im[0]);
  }
}

__global__ void k_zero_stats(double* stats) {
  stats[threadIdx.x] = 0.0;
}

__global__ void k_stats(const double* __restrict__ stats, float2* __restrict__ muinv) {
  int i = threadIdx.x;  // 64
  double n  = 262144.0;
  double mu = stats[2 * i] / n;
  double va = stats[2 * i + 1] / n - mu * mu;
  if (va < 0.0) va = 0.0;
  double sd = sqrt(va);
  muinv[i] = make_float2((float)mu, (float)(1.0 / (sd + 1e-8)));
}

// ------------------------------------------------- K4: conv1(5x5,s2,p2) + BN + ReLU + maxpool2
#define TS1 68
__global__ __launch_bounds__(256) void k_conv1(
    const float* __restrict__ S, const float2* __restrict__ muinv,
    const float* __restrict__ w, const float* __restrict__ cb,
    const float* __restrict__ g, const float* __restrict__ bb,
    const float* __restrict__ bm, const float* __restrict__ bv,
    float* __restrict__ h1) {
  __shared__ float tile[67 * TS1];
  int b = blockIdx.y;
  int by = blockIdx.x >> 3, bx = blockIdx.x & 7;
  int y0 = by * 16, x0 = bx * 16;
  int h0 = 4 * y0 - 2, w0 = 4 * x0 - 2;
  float2 mi = muinv[b];
  const float* Sb = S + (size_t)b * 262144;
  for (int idx = threadIdx.x; idx < 67 * 67; idx += 256) {
    int wl = idx / 67, hl = idx - wl * 67;
    int hh = h0 + hl, ww = w0 + wl;
    float val = 0.0f;
    if (hh >= 0 && hh < 512 && ww >= 0 && ww < 512)
      val = (Sb[(size_t)ww * 512 + hh] - mi.x) * mi.y;
    tile[wl * TS1 + hl] = val;
  }
  __syncthreads();
  int ty = threadIdx.x >> 4, tx = threadIdx.x & 15;
  float in[7][7];
#pragma unroll
  for (int j = 0; j < 7; ++j)
#pragma unroll
    for (int i = 0; i < 7; ++i)
      in[i][j] = tile[(4 * tx + j) * TS1 + 4 * ty + i];
  int Y = y0 + ty, X = x0 + tx;
  for (int occ = 0; occ < 8; ++occ) {
    float w4[4][25];
#pragma unroll
    for (int jo = 0; jo < 4; ++jo)
#pragma unroll
      for (int k = 0; k < 25; ++k)
        w4[jo][k] = w[(occ * 4 + jo) * 25 + k];
#pragma unroll
    for (int jo = 0; jo < 4; ++jo) {
      int oc = occ * 4 + jo;
      float a00 = 0.f, a01 = 0.f, a10 = 0.f, a11 = 0.f;
#pragma unroll
      for (int dy = 0; dy < 5; ++dy)
#pragma unroll
        for (int dx = 0; dx < 5; ++dx) {
          float wv = w4[jo][dy * 5 + dx];
          a00 = fmaf(wv, in[dy][dx], a00);
          a01 = fmaf(wv, in[dy][dx + 2], a01);
          a10 = fmaf(wv, in[dy + 2][dx], a10);
          a11 = fmaf(wv, in[dy + 2][dx + 2], a11);
        }
      float m   = fmaxf(fmaxf(a00, a01), fmaxf(a10, a11));
      float inv = g[oc] / sqrtf(bv[oc] + 1e-5f);
      float sh  = cb[oc] * inv + bb[oc] - bm[oc] * inv;
      h1[(((size_t)b * 32 + oc) * 128 + Y) * 128 + X] = fmaxf(m * inv + sh, 0.0f);
    }
  }
}

// ------------------------------------------------- K5: conv2(3x3,s2,p1,32->64) + BN + ReLU + maxpool2
// v5: round-3 structure (512 thr / 8 waves / 8 oc per wave, 72 VGPR base) +
// T14 async-STAGE split: next ic-tile's global loads issued into registers
// BEFORE the compute phase; LDS write happens after the barrier. HBM/L2
// latency hides under the 4608-FMA compute phase. rv[] fully unrolled ->
// compile-time indices, no scratch (rule #20).
#define TS2 36
__global__ __launch_bounds__(512) void k_conv2(
    const float* __restrict__ h1, const float* __restrict__ w,
    const float* __restrict__ cb, const float* __restrict__ g,
    const float* __restrict__ bb, const float* __restrict__ bm,
    const float* __restrict__ bv, float* __restrict__ h2) {
  __shared__ __attribute__((aligned(16))) float tile[8 * 33 * TS2];  // 38016 B
  int tid = threadIdx.x;
  int b = blockIdx.y;
  int rt = blockIdx.x >> 2, ct = blockIdx.x & 3;
  int ty0 = rt * 16, tx0 = ct * 16;                     // conv-tile origin (16x16 conv)
  int wv = tid >> 6;                                    // wave id 0..7 -> oc subgroup (8 oc)
  int lane = tid & 63;
  int qy = lane >> 3, qx = lane & 7;                    // 8x8 quads = 8x8 pooled outputs
  int iy0 = 2 * ty0 - 1, ix0 = 2 * tx0 - 1;
  int ocbase = wv * 8;
  float acc[8][4];
#pragma unroll
  for (int q = 0; q < 8; ++q)
#pragma unroll
    for (int p = 0; p < 4; ++p) acc[q][p] = 0.0f;

  float rv[18];
  const size_t hb = (size_t)b * 32;

  // ---- staging helpers: 8712 = 512*17 + 8 elements per ic-tile ----
#define C2_LOADR(ICT)                                                          \
  {                                                                            \
    _Pragma("unroll")                                                          \
    for (int k = 0; k < 17; ++k) {                                             \
      int idx = tid + 512 * k;                                                 \
      int ic = idx / 1089;                                                     \
      int rem = idx - ic * 1089;                                               \
      int rr = rem / 33, cc = rem - rr * 33;                                   \
      int iy = iy0 + rr, ix = ix0 + cc;                                        \
      float v = 0.0f;                                                          \
      if (iy >= 0 && iy < 128 && ix >= 0 && ix < 128)                          \
        v = h1[((hb + (ICT) * 8 + ic) * 128 + iy) * 128 + ix];                 \
      rv[k] = v;                                                               \
    }                                                                          \
    if (tid < 8) {                                                             \
      int idx = 8704 + tid;                                                    \
      int ic = idx / 1089;                                                     \
      int rem = idx - ic * 1089;                                               \
      int rr = rem / 33, cc = rem - rr * 33;                                   \
      int iy = iy0 + rr, ix = ix0 + cc;                                        \
      float v = 0.0f;                                                          \
      if (iy >= 0 && iy < 128 && ix >= 0 && ix < 128)                          \
        v = h1[((hb + (ICT) * 8 + ic) * 128 + iy) * 128 + ix];                 \
      rv[17] = v;                                                              \
    }                                                                          \
  }

#define C2_WRITER()                                                            \
  {                                                                            \
    _Pragma("unroll")                                                          \
    for (int k = 0; k < 17; ++k) {                                             \
      int idx = tid + 512 * k;                                                 \
      int ic = idx / 1089;                                                     \
      int rem = idx - ic * 1089;                                               \
      int rr = rem / 33, cc = rem - rr * 33;                                   \
      tile[(ic * 33 + rr) * TS2 + cc] = rv[k];                                 \
    }                                                                          \
    if (tid < 8) {                                                             \
      int idx = 8704 + tid;                                                    \
      int ic = idx / 1089;                                                     \
      int rem = idx - ic * 1089;                                               \
      int rr = rem / 33, cc = rem - rr * 33;                                   \
      tile[(ic * 33 + rr) * TS2 + cc] = rv[17];                                \
    }                                                                          \
  }

  C2_LOADR(0);
  for (int ict = 0; ict < 4; ++ict) {
    __syncthreads();          // previous compute done reading tile
    C2_WRITER();              // (waits vmcnt for rv loads -- issued a phase ago)
    __syncthreads();
    if (ict < 3) C2_LOADR(ict + 1);   // issue next tile's loads early
    int rbase = 4 * qy, cbase = 4 * qx;
#pragma unroll
    for (int ic = 0; ic < 8; ++ic) {
      int icg = ict * 8 + ic;
      float in[5][5];
#pragma unroll
      for (int i = 0; i < 5; ++i) {
        int base = (ic * 33 + rbase + i) * TS2 + cbase;
        float4 a  = *reinterpret_cast<const float4*>(&tile[base]);
        float4 bq = *reinterpret_cast<const float4*>(&tile[base + 4]);
        in[i][0] = a.x; in[i][1] = a.y; in[i][2] = a.z; in[i][3] = a.w;
        in[i][4] = bq.x;
      }
      const float* wic = w + ((size_t)ocbase * 32 + icg) * 9;
#pragma unroll
      for (int q = 0; q < 8; ++q) {
        const float* wo = wic + (size_t)q * 32 * 9;
#pragma unroll
        for (int dy = 0; dy < 3; ++dy)
#pragma unroll
          for (int dx = 0; dx < 3; ++dx) {
            float wvv = wo[dy * 3 + dx];
            acc[q][0] = fmaf(wvv, in[dy][dx],         acc[q][0]);
            acc[q][1] = fmaf(wvv, in[dy][dx + 2],     acc[q][1]);
            acc[q][2] = fmaf(wvv, in[dy + 2][dx],     acc[q][2]);
            acc[q][3] = fmaf(wvv, in[dy + 2][dx + 2], acc[q][3]);
          }
      }
    }
  }
  int Yp = (ty0 >> 1) + qy, Xp = (tx0 >> 1) + qx;
#pragma unroll
  for (int q = 0; q < 8; ++q) {
    int oc = ocbase + q;
    float m   = fmaxf(fmaxf(acc[q][0], acc[q][1]), fmaxf(acc[q][2], acc[q][3]));
    float inv = g[oc] / sqrtf(bv[oc] + 1e-5f);
    float sh  = cb[oc] * inv + bb[oc] - bm[oc] * inv;
    h2[(((size_t)b * 64 + oc) * 32 + Yp) * 32 + Xp] = fmaxf(m * inv + sh, 0.0f);
  }
#undef C2_LOADR
#undef C2_WRITER
}

// ------------------------------------------------- K6: conv3(3x3,s2,p1,64->128) + BN + ReLU + GAP
#define TS3 34
__global__ __launch_bounds__(256) void k_conv3(
    const float* __restrict__ h2, const float* __restrict__ w,
    const float* __restrict__ cb, const float* __restrict__ g,
    const float* __restrict__ bb, const float* __restrict__ bm,
    const float* __restrict__ bv, float* __restrict__ gap) {
  __shared__ __attribute__((aligned(16))) float tile[8 * 33 * TS3];
  __shared__ float red[256];
  int tid = threadIdx.x;
  int ocg = blockIdx.x, b = blockIdx.y;
  int cy = tid >> 4, cx = tid & 15;
  float acc[8];
#pragma unroll
  for (int q = 0; q < 8; ++q) acc[q] = 0.0f;

  for (int ict = 0; ict < 8; ++ict) {
    __syncthreads();
    for (int idx = tid; idx < 8 * 33 * 33; idx += 256) {
      int ic = idx / 1089;
      int rem = idx - ic * 1089;
      int rr = rem / 33, cc = rem - rr * 33;
      int iy = rr - 1, ix = cc - 1;
      float v = 0.0f;
      int icg = ict * 8 + ic;
      if (iy >= 0 && iy < 32 && ix >= 0 && ix < 32)
        v = h2[(((size_t)b * 64 + icg) * 32 + iy) * 32 + ix];
      tile[(ic * 33 + rr) * TS3 + cc] = v;
    }
    __syncthreads();
#pragma unroll
    for (int ic = 0; ic < 8; ++ic) {
      int icg = ict * 8 + ic;
      float in[3][3];
#pragma unroll
      for (int i = 0; i < 3; ++i) {
        const float2* r2 = reinterpret_cast<const float2*>(&tile[(ic * 33 + 2 * cy + i) * TS3 + 2 * cx]);
        float2 a = r2[0];
        in[i][0] = a.x; in[i][1] = a.y;
        in[i][2] = tile[(ic * 33 + 2 * cy + i) * TS3 + 2 * cx + 2];
      }
      const float* wic = w + ((size_t)(ocg * 8) * 64 + icg) * 9;
#pragma unroll
      for (int q = 0; q < 8; ++q) {
        const float* wo = wic + (size_t)q * 64 * 9;
#pragma unroll
        for (int i = 0; i < 3; ++i)
#pragma unroll
          for (int j = 0; j < 3; ++j)
            acc[q] = fmaf(wo[i * 3 + j], in[i][j], acc[q]);
      }
    }
  }
  for (int q = 0; q < 8; ++q) {
    int oc = ocg * 8 + q;
    float inv = g[oc] / sqrtf(bv[oc] + 1e-5f);
    float sh  = cb[oc] * inv + bb[oc] - bm[oc] * inv;
    float val = fmaxf(acc[q] * inv + sh, 0.0f);
    __syncthreads();
    red[tid] = val;
    __syncthreads();
    for (int s = 128; s > 0; s >>= 1) {
      if (tid < s) red[tid] += red[tid + s];
      __syncthreads();
    }
    if (tid == 0) gap[(size_t)b * 128 + oc] = red[0] * (1.0f / 256.0f);
  }
}

// ------------------------------------------------- K7: FC1+ReLU+FC2+ReLU
__global__ __launch_bounds__(256) void k_fc(
    const float* __restrict__ gap,
    const float* __restrict__ w1, const float* __restrict__ b1,
    const float* __restrict__ w2, const float* __restrict__ b2,
    float* __restrict__ out) {
  __shared__ float gv[128], hv[256];
  int b = blockIdx.x, t = threadIdx.x;
  if (t < 128) gv[t] = gap[(size_t)b * 128 + t];
  __syncthreads();
  float a1 = b1[t];
  const float* wr = w1 + (size_t)t * 128;
  for (int k = 0; k < 128; ++k) a1 = fmaf(wr[k], gv[k], a1);
  hv[t] = fmaxf(a1, 0.0f);
  __syncthreads();
  if (t < 128) {
    float a2 = b2[t];
    const float* wr2 = w2 + (size_t)t * 256;
    for (int k = 0; k < 256; ++k) a2 = fmaf(wr2[k], hv[k], a2);
    out[(size_t)b * 128 + t] = fmaxf(a2, 0.0f);
  }
}

// ================================================================ launch
extern "C" void kernel_launch(void* const* d_in, const int* in_sizes, int n_in,
                              void* d_out, int out_size, void* d_ws, size_t ws_size,
                              hipStream_t stream) {
  (void)in_sizes; (void)n_in; (void)out_size; (void)ws_size;
  const float* x   = (const float*)d_in[0];
  const float* c1w = (const float*)d_in[1];
  const float* c1b = (const float*)d_in[2];
  const float* b1g = (const float*)d_in[3];
  const float* b1b = (const float*)d_in[4];
  const float* b1m = (const float*)d_in[5];
  const float* b1v = (const float*)d_in[6];
  const float* c2w = (const float*)d_in[7];
  const float* c2b = (const float*)d_in[8];
  const float* b2g = (const float*)d_in[9];
  const float* b2b = (const float*)d_in[10];
  const float* b2m = (const float*)d_in[11];
  const float* b2v = (const float*)d_in[12];
  const float* c3w = (const float*)d_in[13];
  const float* c3b = (const float*)d_in[14];
  const float* b3g = (const float*)d_in[15];
  const float* b3b = (const float*)d_in[16];
  const float* b3m = (const float*)d_in[17];
  const float* b3v = (const float*)d_in[18];
  const float* f1w = (const float*)d_in[19];
  const float* f1b = (const float*)d_in[20];
  const float* f2w = (const float*)d_in[21];
  const float* f2b = (const float*)d_in[22];
  float* out = (float*)d_out;

  char* ws = (char*)d_ws;
  float2* G     = (float2*)(ws + 0);
  float2* GT    = (float2*)(ws + 67633152ull);
  float*  S     = (float*) (ws + 135266304ull);
  double* stats = (double*)(ws + 202375168ull);
  float2* muinv = (float2*)(ws + 202376192ull);
  float*  gap   = (float*) (ws + 202376704ull);
  float*  h1    = (float*) (ws + 0);
  float*  h2    = (float*) (ws + 135266304ull);

  k_zero_stats<<<1, 128, 0, stream>>>(stats);
  k_rowfft   <<<dim3(256, 64), 256, 0, stream>>>(x, G);
  k_transpose<<<dim3(9, 16, 64), dim3(32, 8), 0, stream>>>(G, GT);
  k_colfft   <<<dim3(257, 64), 256, 0, stream>>>(GT, S, stats);
  k_stats    <<<1, 64, 0, stream>>>(stats, muinv);
  k_conv1    <<<dim3(64, 64), 256, 0, stream>>>(S, muinv, c1w, c1b, b1g, b1b, b1m, b1v, h1);
  k_conv2    <<<dim3(16, 64), 512, 0, stream>>>(h1, c2w, c2b, b2g, b2b, b2m, b2v, h2);
  k_conv3    <<<dim3(16, 64), 256, 0, stream>>>(h2, c3w, c3b, b3g, b3b, b3m, b3v, gap);
  k_fc       <<<64, 256, 0, stream>>>(gap, f1w, f1b, f2w, f2b, out);
}

// Round 6
// 1000.106 us; speedup vs baseline: 1.1988x; 1.0258x over previous
//
#include <hip/hip_runtime.h>
#include <math.h>

#define PI_F 3.14159265358979323846f
#define KS 258   // padded column count of half-spectrum G (k in [0,256], stride 258)

typedef float f2 __attribute__((ext_vector_type(2)));

// ---------------------------------------------------------------- FFT core
__device__ __forceinline__ void fft512(float* re, float* im,
                                       const float* twr, const float* twi, int t) {
#pragma unroll
  for (int s = 0; s < 9; ++s) {
    __syncthreads();
    int h  = 1 << s;
    int j  = t & (h - 1);
    int i1 = ((t >> s) << (s + 1)) + j;
    int i2 = i1 + h;
    int ti = j << (8 - s);
    float wr = twr[ti], wi = twi[ti];
    float ur = re[i1], ui = im[i1];
    float vr = re[i2], vi = im[i2];
    float tr = vr * wr - vi * wi;
    float tq = vr * wi + vi * wr;
    re[i1] = ur + tr; im[i1] = ui + tq;
    re[i2] = ur - tr; im[i2] = ui - tq;
  }
}

__device__ __forceinline__ void init_tw(float* twr, float* twi, int t) {
  float s, c;
  sincosf(-2.0f * PI_F * (float)t * (1.0f / 512.0f), &s, &c);
  twr[t] = c; twi[t] = s;
}

// ------------------------------------------------- K1: gray + paired-row FFT (Hermitian pack)
__global__ __launch_bounds__(256) void k_rowfft(const float* __restrict__ x,
                                                float2* __restrict__ G) {
  __shared__ float re[512], im[512], twr[256], twi[256];
  int t = threadIdx.x;
  int q = blockIdx.x;
  int b = blockIdx.y;
  int r0 = 2 * q;
  const float* xb = x + ((size_t)b * 3 * 512 + r0) * 512;
  float a0 = 0.299f * xb[t]           + 0.587f * xb[262144 + t]           + 0.114f * xb[524288 + t];
  float a1 = 0.299f * xb[t + 256]     + 0.587f * xb[262144 + t + 256]     + 0.114f * xb[524288 + t + 256];
  float c0 = 0.299f * xb[512 + t]     + 0.587f * xb[262656 + t]           + 0.114f * xb[524800 + t];
  float c1 = 0.299f * xb[512 + t + 256] + 0.587f * xb[262656 + t + 256]   + 0.114f * xb[524800 + t + 256];
  int rv0 = __brev((unsigned)t) >> 23;
  int rv1 = __brev((unsigned)(t + 256)) >> 23;
  re[rv0] = a0; im[rv0] = c0;
  re[rv1] = a1; im[rv1] = c1;
  init_tw(twr, twi, t);
  fft512(re, im, twr, twi, t);
  __syncthreads();
  float2* G0 = G + ((size_t)b * 512 + r0) * KS;
  float2* G1 = G0 + KS;
  for (int k = t; k <= 256; k += 256) {
    int mk = (512 - k) & 511;
    float zr = re[k], zi = im[k];
    float mr = re[mk], mi = im[mk];
    G0[k] = make_float2(0.5f * (zr + mr), 0.5f * (zi - mi));
    G1[k] = make_float2(0.5f * (zi + mi), 0.5f * (mr - zr));
  }
}

// ------------------------------------------------- K1.5: out-of-place transpose G -> GT
__global__ __launch_bounds__(256) void k_transpose(const float2* __restrict__ G,
                                                   float2* __restrict__ GT) {
  __shared__ float2 ta[32][33];
  int kt = blockIdx.x, rt = blockIdx.y, b = blockIdx.z;
  int tx = threadIdx.x, ty = threadIdx.y;
  int k0 = kt * 32, r0 = rt * 32;
  const float2* Gb = G + (size_t)b * 512 * KS;
  float2* GTb = GT + (size_t)b * KS * 512;
#pragma unroll
  for (int i = 0; i < 32; i += 8) {
    int k = k0 + tx;
    float2 v = make_float2(0.0f, 0.0f);
    if (k < KS) v = Gb[(size_t)(r0 + ty + i) * KS + k];
    ta[ty + i][tx] = v;
  }
  __syncthreads();
#pragma unroll
  for (int i = 0; i < 32; i += 8) {
    int k = k0 + ty + i;
    if (k < KS) GTb[(size_t)k * 512 + r0 + tx] = ta[tx][ty + i];
  }
}

// ------------------------------------------------- K2: column FFT + mag/log1p/fftshift + mirror + stats
__global__ __launch_bounds__(256) void k_colfft(const float2* __restrict__ GT,
                                                float* __restrict__ S,
                                                double* __restrict__ stats) {
  __shared__ float re[512], im[512], twr[256], twi[256];
  int t  = threadIdx.x;
  int kc = blockIdx.x;
  int b  = blockIdx.y;
  const float2* Gc = GT + ((size_t)b * KS + kc) * 512;
  float2 v0 = Gc[t], v1 = Gc[t + 256];
  int rv0 = __brev((unsigned)t) >> 23;
  int rv1 = __brev((unsigned)(t + 256)) >> 23;
  re[rv0] = v0.x; im[rv0] = v0.y;
  re[rv1] = v1.x; im[rv1] = v1.y;
  init_tw(twr, twi, t);
  fft512(re, im, twr, twi, t);
  float m0 = log1pf(sqrtf(re[t] * re[t] + im[t] * im[t]));
  float m1 = log1pf(sqrtf(re[t + 256] * re[t + 256] + im[t + 256] * im[t + 256]));
  int v = (kc + 256) & 511;
  float* Sb = S + (size_t)b * 262144;
  Sb[(size_t)v * 512 + t + 256] = m0;
  Sb[(size_t)v * 512 + t]       = m1;
  bool mir = (kc >= 1) && (kc <= 255);
  if (mir) {
    int vp = 256 - kc;
    Sb[(size_t)vp * 512 + ((256 - t) & 511)] = m0;
    Sb[(size_t)vp * 512 + ((512 - t) & 511)] = m1;
  }
  __syncthreads();
  re[t] = m0 + m1;
  im[t] = m0 * m0 + m1 * m1;
  __syncthreads();
  for (int s = 128; s > 0; s >>= 1) {
    if (t < s) { re[t] += re[t + s]; im[t] += im[t + s]; }
    __syncthreads();
  }
  if (t == 0) {
    double wgt = mir ? 2.0 : 1.0;
    atomicAdd(&stats[2 * b],     wgt * (double)re[0]);
    atomicAdd(&stats[2 * b + 1], wgt * (double)im[0]);
  }
}

__global__ void k_zero_stats(double* stats) {
  stats[threadIdx.x] = 0.0;
}

__global__ void k_stats(const double* __restrict__ stats, float2* __restrict__ muinv) {
  int i = threadIdx.x;  // 64
  double n  = 262144.0;
  double mu = stats[2 * i] / n;
  double va = stats[2 * i + 1] / n - mu * mu;
  if (va < 0.0) va = 0.0;
  double sd = sqrt(va);
  muinv[i] = make_float2((float)mu, (float)(1.0 / (sd + 1e-8)));
}

// ------------------------------------------------- K4: conv1(5x5,s2,p2) + BN + ReLU + maxpool2
#define TS1 68
__global__ __launch_bounds__(256) void k_conv1(
    const float* __restrict__ S, const float2* __restrict__ muinv,
    const float* __restrict__ w, const float* __restrict__ cb,
    const float* __restrict__ g, const float* __restrict__ bb,
    const float* __restrict__ bm, const float* __restrict__ bv,
    float* __restrict__ h1) {
  __shared__ float tile[67 * TS1];
  int b = blockIdx.y;
  int by = blockIdx.x >> 3, bx = blockIdx.x & 7;
  int y0 = by * 16, x0 = bx * 16;
  int h0 = 4 * y0 - 2, w0 = 4 * x0 - 2;
  float2 mi = muinv[b];
  const float* Sb = S + (size_t)b * 262144;
  for (int idx = threadIdx.x; idx < 67 * 67; idx += 256) {
    int wl = idx / 67, hl = idx - wl * 67;
    int hh = h0 + hl, ww = w0 + wl;
    float val = 0.0f;
    if (hh >= 0 && hh < 512 && ww >= 0 && ww < 512)
      val = (Sb[(size_t)ww * 512 + hh] - mi.x) * mi.y;
    tile[wl * TS1 + hl] = val;
  }
  __syncthreads();
  int ty = threadIdx.x >> 4, tx = threadIdx.x & 15;
  float in[7][7];
#pragma unroll
  for (int j = 0; j < 7; ++j)
#pragma unroll
    for (int i = 0; i < 7; ++i)
      in[i][j] = tile[(4 * tx + j) * TS1 + 4 * ty + i];
  int Y = y0 + ty, X = x0 + tx;
  for (int occ = 0; occ < 8; ++occ) {
    float w4[4][25];
#pragma unroll
    for (int jo = 0; jo < 4; ++jo)
#pragma unroll
      for (int k = 0; k < 25; ++k)
        w4[jo][k] = w[(occ * 4 + jo) * 25 + k];
#pragma unroll
    for (int jo = 0; jo < 4; ++jo) {
      int oc = occ * 4 + jo;
      float a00 = 0.f, a01 = 0.f, a10 = 0.f, a11 = 0.f;
#pragma unroll
      for (int dy = 0; dy < 5; ++dy)
#pragma unroll
        for (int dx = 0; dx < 5; ++dx) {
          float wv = w4[jo][dy * 5 + dx];
          a00 = fmaf(wv, in[dy][dx], a00);
          a01 = fmaf(wv, in[dy][dx + 2], a01);
          a10 = fmaf(wv, in[dy + 2][dx], a10);
          a11 = fmaf(wv, in[dy + 2][dx + 2], a11);
        }
      float m   = fmaxf(fmaxf(a00, a01), fmaxf(a10, a11));
      float inv = g[oc] / sqrtf(bv[oc] + 1e-5f);
      float sh  = cb[oc] * inv + bb[oc] - bm[oc] * inv;
      h1[(((size_t)b * 32 + oc) * 128 + Y) * 128 + X] = fmaxf(m * inv + sh, 0.0f);
    }
  }
}

// ------------------------------------------------- K5: conv2(3x3,s2,p1,32->64) + BN + ReLU + maxpool2
// v6: v5 (T14 async-STAGE, 8 waves x 8 oc) + PACKED v_pk_fma_f32 inner loop.
// acc pairs {a00,a01} / {a10,a11} share the weight; inputs packed as
// P[i][dx] = {t[i][dx], t[i][dx+2]} -> FMA instruction count halves (9216->4608).
#define TS2 36
__global__ __launch_bounds__(512) void k_conv2(
    const float* __restrict__ h1, const float* __restrict__ w,
    const float* __restrict__ cb, const float* __restrict__ g,
    const float* __restrict__ bb, const float* __restrict__ bm,
    const float* __restrict__ bv, float* __restrict__ h2) {
  __shared__ __attribute__((aligned(16))) float tile[8 * 33 * TS2];  // 38016 B
  int tid = threadIdx.x;
  int b = blockIdx.y;
  int rt = blockIdx.x >> 2, ct = blockIdx.x & 3;
  int ty0 = rt * 16, tx0 = ct * 16;                     // conv-tile origin (16x16 conv)
  int wv = tid >> 6;                                    // wave id 0..7 -> oc subgroup (8 oc)
  int lane = tid & 63;
  int qy = lane >> 3, qx = lane & 7;                    // 8x8 quads = 8x8 pooled outputs
  int iy0 = 2 * ty0 - 1, ix0 = 2 * tx0 - 1;
  int ocbase = wv * 8;
  f2 accA[8], accB[8];
#pragma unroll
  for (int q = 0; q < 8; ++q) {
    accA[q] = (f2){0.0f, 0.0f};
    accB[q] = (f2){0.0f, 0.0f};
  }

  float rv[18];
  const size_t hb = (size_t)b * 32;

  // ---- staging helpers: 8712 = 512*17 + 8 elements per ic-tile ----
#define C2_LOADR(ICT)                                                          \
  {                                                                            \
    _Pragma("unroll")                                                          \
    for (int k = 0; k < 17; ++k) {                                             \
      int idx = tid + 512 * k;                                                 \
      int ic = idx / 1089;                                                     \
      int rem = idx - ic * 1089;                                               \
      int rr = rem / 33, cc = rem - rr * 33;                                   \
      int iy = iy0 + rr, ix = ix0 + cc;                                        \
      float v = 0.0f;                                                          \
      if (iy >= 0 && iy < 128 && ix >= 0 && ix < 128)                          \
        v = h1[((hb + (ICT) * 8 + ic) * 128 + iy) * 128 + ix];                 \
      rv[k] = v;                                                               \
    }                                                                          \
    if (tid < 8) {                                                             \
      int idx = 8704 + tid;                                                    \
      int ic = idx / 1089;                                                     \
      int rem = idx - ic * 1089;                                               \
      int rr = rem / 33, cc = rem - rr * 33;                                   \
      int iy = iy0 + rr, ix = ix0 + cc;                                        \
      float v = 0.0f;                                                          \
      if (iy >= 0 && iy < 128 && ix >= 0 && ix < 128)                          \
        v = h1[((hb + (ICT) * 8 + ic) * 128 + iy) * 128 + ix];                 \
      rv[17] = v;                                                              \
    }                                                                          \
  }

#define C2_WRITER()                                                            \
  {                                                                            \
    _Pragma("unroll")                                                          \
    for (int k = 0; k < 17; ++k) {                                             \
      int idx = tid + 512 * k;                                                 \
      int ic = idx / 1089;                                                     \
      int rem = idx - ic * 1089;                                               \
      int rr = rem / 33, cc = rem - rr * 33;                                   \
      tile[(ic * 33 + rr) * TS2 + cc] = rv[k];                                 \
    }                                                                          \
    if (tid < 8) {                                                             \
      int idx = 8704 + tid;                                                    \
      int ic = idx / 1089;                                                     \
      int rem = idx - ic * 1089;                                               \
      int rr = rem / 33, cc = rem - rr * 33;                                   \
      tile[(ic * 33 + rr) * TS2 + cc] = rv[17];                                \
    }                                                                          \
  }

  C2_LOADR(0);
  for (int ict = 0; ict < 4; ++ict) {
    __syncthreads();          // previous compute done reading tile
    C2_WRITER();              // (waits vmcnt for rv loads -- issued a phase ago)
    __syncthreads();
    if (ict < 3) C2_LOADR(ict + 1);   // issue next tile's loads early
    int rbase = 4 * qy, cbase = 4 * qx;
#pragma unroll
    for (int ic = 0; ic < 8; ++ic) {
      int icg = ict * 8 + ic;
      f2 P[5][3];
#pragma unroll
      for (int i = 0; i < 5; ++i) {
        int base = (ic * 33 + rbase + i) * TS2 + cbase;
        float4 a  = *reinterpret_cast<const float4*>(&tile[base]);
        float4 bq = *reinterpret_cast<const float4*>(&tile[base + 4]);
        P[i][0] = (f2){a.x, a.z};
        P[i][1] = (f2){a.y, a.w};
        P[i][2] = (f2){a.z, bq.x};
      }
      const float* wic = w + ((size_t)ocbase * 32 + icg) * 9;
#pragma unroll
      for (int q = 0; q < 8; ++q) {
        const float* wo = wic + (size_t)q * 32 * 9;
#pragma unroll
        for (int dy = 0; dy < 3; ++dy)
#pragma unroll
          for (int dx = 0; dx < 3; ++dx) {
            float wvv = wo[dy * 3 + dx];
            f2 wv2 = (f2){wvv, wvv};
            accA[q] = __builtin_elementwise_fma(wv2, P[dy][dx],     accA[q]);
            accB[q] = __builtin_elementwise_fma(wv2, P[dy + 2][dx], accB[q]);
          }
      }
    }
  }
  int Yp = (ty0 >> 1) + qy, Xp = (tx0 >> 1) + qx;
#pragma unroll
  for (int q = 0; q < 8; ++q) {
    int oc = ocbase + q;
    float m   = fmaxf(fmaxf(accA[q].x, accA[q].y), fmaxf(accB[q].x, accB[q].y));
    float inv = g[oc] / sqrtf(bv[oc] + 1e-5f);
    float sh  = cb[oc] * inv + bb[oc] - bm[oc] * inv;
    h2[(((size_t)b * 64 + oc) * 32 + Yp) * 32 + Xp] = fmaxf(m * inv + sh, 0.0f);
  }
#undef C2_LOADR
#undef C2_WRITER
}

// ------------------------------------------------- K6: conv3(3x3,s2,p1,64->128) + BN + ReLU + GAP
#define TS3 34
__global__ __launch_bounds__(256) void k_conv3(
    const float* __restrict__ h2, const float* __restrict__ w,
    const float* __restrict__ cb, const float* __restrict__ g,
    const float* __restrict__ bb, const float* __restrict__ bm,
    const float* __restrict__ bv, float* __restrict__ gap) {
  __shared__ __attribute__((aligned(16))) float tile[8 * 33 * TS3];
  __shared__ float red[256];
  int tid = threadIdx.x;
  int ocg = blockIdx.x, b = blockIdx.y;
  int cy = tid >> 4, cx = tid & 15;
  float acc[8];
#pragma unroll
  for (int q = 0; q < 8; ++q) acc[q] = 0.0f;

  for (int ict = 0; ict < 8; ++ict) {
    __syncthreads();
    for (int idx = tid; idx < 8 * 33 * 33; idx += 256) {
      int ic = idx / 1089;
      int rem = idx - ic * 1089;
      int rr = rem / 33, cc = rem - rr * 33;
      int iy = rr - 1, ix = cc - 1;
      float v = 0.0f;
      int icg = ict * 8 + ic;
      if (iy >= 0 && iy < 32 && ix >= 0 && ix < 32)
        v = h2[(((size_t)b * 64 + icg) * 32 + iy) * 32 + ix];
      tile[(ic * 33 + rr) * TS3 + cc] = v;
    }
    __syncthreads();
#pragma unroll
    for (int ic = 0; ic < 8; ++ic) {
      int icg = ict * 8 + ic;
      float in[3][3];
#pragma unroll
      for (int i = 0; i < 3; ++i) {
        const float2* r2 = reinterpret_cast<const float2*>(&tile[(ic * 33 + 2 * cy + i) * TS3 + 2 * cx]);
        float2 a = r2[0];
        in[i][0] = a.x; in[i][1] = a.y;
        in[i][2] = tile[(ic * 33 + 2 * cy + i) * TS3 + 2 * cx + 2];
      }
      const float* wic = w + ((size_t)(ocg * 8) * 64 + icg) * 9;
#pragma unroll
      for (int q = 0; q < 8; ++q) {
        const float* wo = wic + (size_t)q * 64 * 9;
#pragma unroll
        for (int i = 0; i < 3; ++i)
#pragma unroll
          for (int j = 0; j < 3; ++j)
            acc[q] = fmaf(wo[i * 3 + j], in[i][j], acc[q]);
      }
    }
  }
  for (int q = 0; q < 8; ++q) {
    int oc = ocg * 8 + q;
    float inv = g[oc] / sqrtf(bv[oc] + 1e-5f);
    float sh  = cb[oc] * inv + bb[oc] - bm[oc] * inv;
    float val = fmaxf(acc[q] * inv + sh, 0.0f);
    __syncthreads();
    red[tid] = val;
    __syncthreads();
    for (int s = 128; s > 0; s >>= 1) {
      if (tid < s) red[tid] += red[tid + s];
      __syncthreads();
    }
    if (tid == 0) gap[(size_t)b * 128 + oc] = red[0] * (1.0f / 256.0f);
  }
}

// ------------------------------------------------- K7: FC1+ReLU+FC2+ReLU
__global__ __launch_bounds__(256) void k_fc(
    const float* __restrict__ gap,
    const float* __restrict__ w1, const float* __restrict__ b1,
    const float* __restrict__ w2, const float* __restrict__ b2,
    float* __restrict__ out) {
  __shared__ float gv[128], hv[256];
  int b = blockIdx.x, t = threadIdx.x;
  if (t < 128) gv[t] = gap[(size_t)b * 128 + t];
  __syncthreads();
  float a1 = b1[t];
  const float* wr = w1 + (size_t)t * 128;
  for (int k = 0; k < 128; ++k) a1 = fmaf(wr[k], gv[k], a1);
  hv[t] = fmaxf(a1, 0.0f);
  __syncthreads();
  if (t < 128) {
    float a2 = b2[t];
    const float* wr2 = w2 + (size_t)t * 256;
    for (int k = 0; k < 256; ++k) a2 = fmaf(wr2[k], hv[k], a2);
    out[(size_t)b * 128 + t] = fmaxf(a2, 0.0f);
  }
}

// ================================================================ launch
extern "C" void kernel_launch(void* const* d_in, const int* in_sizes, int n_in,
                              void* d_out, int out_size, void* d_ws, size_t ws_size,
                              hipStream_t stream) {
  (void)in_sizes; (void)n_in; (void)out_size; (void)ws_size;
  const float* x   = (const float*)d_in[0];
  const float* c1w = (const float*)d_in[1];
  const float* c1b = (const float*)d_in[2];
  const float* b1g = (const float*)d_in[3];
  const float* b1b = (const float*)d_in[4];
  const float* b1m = (const float*)d_in[5];
  const float* b1v = (const float*)d_in[6];
  const float* c2w = (const float*)d_in[7];
  const float* c2b = (const float*)d_in[8];
  const float* b2g = (const float*)d_in[9];
  const float* b2b = (const float*)d_in[10];
  const float* b2m = (const float*)d_in[11];
  const float* b2v = (const float*)d_in[12];
  const float* c3w = (const float*)d_in[13];
  const float* c3b = (const float*)d_in[14];
  const float* b3g = (const float*)d_in[15];
  const float* b3b = (const float*)d_in[16];
  const float* b3m = (const float*)d_in[17];
  const float* b3v = (const float*)d_in[18];
  const float* f1w = (const float*)d_in[19];
  const float* f1b = (const float*)d_in[20];
  const float* f2w = (const float*)d_in[21];
  const float* f2b = (const float*)d_in[22];
  float* out = (float*)d_out;

  char* ws = (char*)d_ws;
  float2* G     = (float2*)(ws + 0);
  float2* GT    = (float2*)(ws + 67633152ull);
  float*  S     = (float*) (ws + 135266304ull);
  double* stats = (double*)(ws + 202375168ull);
  float2* muinv = (float2*)(ws + 202376192ull);
  float*  gap   = (float*) (ws + 202376704ull);
  float*  h1    = (float*) (ws + 0);
  float*  h2    = (float*) (ws + 135266304ull);

  k_zero_stats<<<1, 128, 0, stream>>>(stats);
  k_rowfft   <<<dim3(256, 64), 256, 0, stream>>>(x, G);
  k_transpose<<<dim3(9, 16, 64), dim3(32, 8), 0, stream>>>(G, GT);
  k_colfft   <<<dim3(257, 64), 256, 0, stream>>>(GT, S, stats);
  k_stats    <<<1, 64, 0, stream>>>(stats, muinv);
  k_conv1    <<<dim3(64, 64), 256, 0, stream>>>(S, muinv, c1w, c1b, b1g, b1b, b1m, b1v, h1);
  k_conv2    <<<dim3(16, 64), 512, 0, stream>>>(h1, c2w, c2b, b2g, b2b, b2m, b2v, h2);
  k_conv3    <<<dim3(16, 64), 256, 0, stream>>>(h2, c3w, c3b, b3g, b3b, b3m, b3v, gap);
  k_fc       <<<64, 256, 0, stream>>>(gap, f1w, f1b, f2w, f2b, out);
}

// Round 7
// 994.061 us; speedup vs baseline: 1.2061x; 1.0061x over previous
//
#include <hip/hip_runtime.h>
#include <math.h>

#define PI_F 3.14159265358979323846f
#define KS 258   // padded column count of half-spectrum G (k in [0,256], stride 258)

typedef float f2 __attribute__((ext_vector_type(2)));

// ---------------------------------------------------------------- FFT core
// v2: two radix-2 stages fused per LDS round trip. 128 active threads own
// 4-element groups {a, a+h, a+2h, a+3h} (closed under stages s and s+1):
//   stage s   pairs (a,a+h),(a+2h,a+3h)   tw idx j<<(8-s), j = a&(h-1)
//   stage s+1 pairs (a,a+2h),(a+h,a+3h)   tw idx j<<(7-s) and (j+h)<<(7-s)
// 9 stages -> 4 fused double-stages + final s=8 stage. 5 LDS round trips
// (10.2K b32/FFT) + 6 barriers vs 9 round trips (18.4K) + 10 barriers.
__device__ __forceinline__ void fft512(float* re, float* im,
                                       const float* twr, const float* twi, int t) {
  bool act = (t < 128);
  int u = t;
#pragma unroll
  for (int s = 0; s < 8; s += 2) {
    __syncthreads();
    if (act) {
      int h  = 1 << s;
      int j  = u & (h - 1);
      int a  = ((u >> s) << (s + 2)) + j;
      int i0 = a, i1 = a + h, i2 = a + 2 * h, i3 = a + 3 * h;
      float e0r = re[i0], e0i = im[i0];
      float e1r = re[i1], e1i = im[i1];
      float e2r = re[i2], e2i = im[i2];
      float e3r = re[i3], e3i = im[i3];
      int tis = j << (8 - s);
      float wsr = twr[tis], wsi = twi[tis];
      // stage s
      float t1r = e1r * wsr - e1i * wsi, t1i = e1r * wsi + e1i * wsr;
      float t3r = e3r * wsr - e3i * wsi, t3i = e3r * wsi + e3i * wsr;
      float b0r = e0r + t1r, b0i = e0i + t1i;
      float b1r = e0r - t1r, b1i = e0i - t1i;
      float b2r = e2r + t3r, b2i = e2i + t3i;
      float b3r = e2r - t3r, b3i = e2i - t3i;
      // stage s+1
      int ti0 = j << (7 - s);
      int ti1 = (j + h) << (7 - s);
      float w0r = twr[ti0], w0i = twi[ti0];
      float w1r = twr[ti1], w1i = twi[ti1];
      float u2r = b2r * w0r - b2i * w0i, u2i = b2r * w0i + b2i * w0r;
      float u3r = b3r * w1r - b3i * w1i, u3i = b3r * w1i + b3i * w1r;
      re[i0] = b0r + u2r; im[i0] = b0i + u2i;
      re[i2] = b0r - u2r; im[i2] = b0i - u2i;
      re[i1] = b1r + u3r; im[i1] = b1i + u3i;
      re[i3] = b1r - u3r; im[i3] = b1i - u3i;
    }
  }
  // final stage s=8 (h=256): 2 butterflies per active thread
  __syncthreads();
  if (act) {
#pragma unroll
    for (int k = 0; k < 2; ++k) {
      int i1 = u + k * 128;
      int i2 = i1 + 256;
      float wr = twr[i1], wi = twi[i1];
      float ur = re[i1], ui = im[i1];
      float vr = re[i2], vi = im[i2];
      float tr = vr * wr - vi * wi;
      float tq = vr * wi + vi * wr;
      re[i1] = ur + tr; im[i1] = ui + tq;
      re[i2] = ur - tr; im[i2] = ui - tq;
    }
  }
  __syncthreads();   // results visible to all threads (callers read cross-thread)
}

__device__ __forceinline__ void init_tw(float* twr, float* twi, int t) {
  float s, c;
  sincosf(-2.0f * PI_F * (float)t * (1.0f / 512.0f), &s, &c);
  twr[t] = c; twi[t] = s;
}

// ------------------------------------------------- K1: gray + paired-row FFT (Hermitian pack)
__global__ __launch_bounds__(256) void k_rowfft(const float* __restrict__ x,
                                                float2* __restrict__ G) {
  __shared__ float re[512], im[512], twr[256], twi[256];
  int t = threadIdx.x;
  int q = blockIdx.x;
  int b = blockIdx.y;
  int r0 = 2 * q;
  const float* xb = x + ((size_t)b * 3 * 512 + r0) * 512;
  float a0 = 0.299f * xb[t]           + 0.587f * xb[262144 + t]           + 0.114f * xb[524288 + t];
  float a1 = 0.299f * xb[t + 256]     + 0.587f * xb[262144 + t + 256]     + 0.114f * xb[524288 + t + 256];
  float c0 = 0.299f * xb[512 + t]     + 0.587f * xb[262656 + t]           + 0.114f * xb[524800 + t];
  float c1 = 0.299f * xb[512 + t + 256] + 0.587f * xb[262656 + t + 256]   + 0.114f * xb[524800 + t + 256];
  int rv0 = __brev((unsigned)t) >> 23;
  int rv1 = __brev((unsigned)(t + 256)) >> 23;
  re[rv0] = a0; im[rv0] = c0;
  re[rv1] = a1; im[rv1] = c1;
  init_tw(twr, twi, t);
  fft512(re, im, twr, twi, t);
  float2* G0 = G + ((size_t)b * 512 + r0) * KS;
  float2* G1 = G0 + KS;
  for (int k = t; k <= 256; k += 256) {
    int mk = (512 - k) & 511;
    float zr = re[k], zi = im[k];
    float mr = re[mk], mi = im[mk];
    G0[k] = make_float2(0.5f * (zr + mr), 0.5f * (zi - mi));
    G1[k] = make_float2(0.5f * (zi + mi), 0.5f * (mr - zr));
  }
}

// ------------------------------------------------- K1.5: out-of-place transpose G -> GT
__global__ __launch_bounds__(256) void k_transpose(const float2* __restrict__ G,
                                                   float2* __restrict__ GT) {
  __shared__ float2 ta[32][33];
  int kt = blockIdx.x, rt = blockIdx.y, b = blockIdx.z;
  int tx = threadIdx.x, ty = threadIdx.y;
  int k0 = kt * 32, r0 = rt * 32;
  const float2* Gb = G + (size_t)b * 512 * KS;
  float2* GTb = GT + (size_t)b * KS * 512;
#pragma unroll
  for (int i = 0; i < 32; i += 8) {
    int k = k0 + tx;
    float2 v = make_float2(0.0f, 0.0f);
    if (k < KS) v = Gb[(size_t)(r0 + ty + i) * KS + k];
    ta[ty + i][tx] = v;
  }
  __syncthreads();
#pragma unroll
  for (int i = 0; i < 32; i += 8) {
    int k = k0 + ty + i;
    if (k < KS) GTb[(size_t)k * 512 + r0 + tx] = ta[tx][ty + i];
  }
}

// ------------------------------------------------- K2: column FFT + mag/log1p/fftshift + mirror + stats
__global__ __launch_bounds__(256) void k_colfft(const float2* __restrict__ GT,
                                                float* __restrict__ S,
                                                double* __restrict__ stats) {
  __shared__ float re[512], im[512], twr[256], twi[256];
  __shared__ float ws1[4], ws2[4];
  int t  = threadIdx.x;
  int kc = blockIdx.x;
  int b  = blockIdx.y;
  const float2* Gc = GT + ((size_t)b * KS + kc) * 512;
  float2 v0 = Gc[t], v1 = Gc[t + 256];
  int rv0 = __brev((unsigned)t) >> 23;
  int rv1 = __brev((unsigned)(t + 256)) >> 23;
  re[rv0] = v0.x; im[rv0] = v0.y;
  re[rv1] = v1.x; im[rv1] = v1.y;
  init_tw(twr, twi, t);
  fft512(re, im, twr, twi, t);
  float m0 = log1pf(sqrtf(re[t] * re[t] + im[t] * im[t]));
  float m1 = log1pf(sqrtf(re[t + 256] * re[t + 256] + im[t + 256] * im[t + 256]));
  int v = (kc + 256) & 511;
  float* Sb = S + (size_t)b * 262144;
  Sb[(size_t)v * 512 + t + 256] = m0;
  Sb[(size_t)v * 512 + t]       = m1;
  bool mir = (kc >= 1) && (kc <= 255);
  if (mir) {
    int vp = 256 - kc;
    Sb[(size_t)vp * 512 + ((256 - t) & 511)] = m0;
    Sb[(size_t)vp * 512 + ((512 - t) & 511)] = m1;
  }
  // stats: wave shuffle reduce (no barrier-tree, no re/im reuse)
  float s1 = m0 + m1;
  float s2 = m0 * m0 + m1 * m1;
#pragma unroll
  for (int off = 32; off > 0; off >>= 1) {
    s1 += __shfl_down(s1, off);
    s2 += __shfl_down(s2, off);
  }
  int wvid = t >> 6;
  if ((t & 63) == 0) { ws1[wvid] = s1; ws2[wvid] = s2; }
  __syncthreads();
  if (t == 0) {
    float a = ws1[0] + ws1[1] + ws1[2] + ws1[3];
    float c = ws2[0] + ws2[1] + ws2[2] + ws2[3];
    double wgt = mir ? 2.0 : 1.0;
    atomicAdd(&stats[2 * b],     wgt * (double)a);
    atomicAdd(&stats[2 * b + 1], wgt * (double)c);
  }
}

__global__ void k_zero_stats(double* stats) {
  stats[threadIdx.x] = 0.0;
}

__global__ void k_stats(const double* __restrict__ stats, float2* __restrict__ muinv) {
  int i = threadIdx.x;  // 64
  double n  = 262144.0;
  double mu = stats[2 * i] / n;
  double va = stats[2 * i + 1] / n - mu * mu;
  if (va < 0.0) va = 0.0;
  double sd = sqrt(va);
  muinv[i] = make_float2((float)mu, (float)(1.0 / (sd + 1e-8)));
}

// ------------------------------------------------- K4: conv1(5x5,s2,p2) + BN + ReLU + maxpool2
#define TS1 68
__global__ __launch_bounds__(256) void k_conv1(
    const float* __restrict__ S, const float2* __restrict__ muinv,
    const float* __restrict__ w, const float* __restrict__ cb,
    const float* __restrict__ g, const float* __restrict__ bb,
    const float* __restrict__ bm, const float* __restrict__ bv,
    float* __restrict__ h1) {
  __shared__ float tile[67 * TS1];
  int b = blockIdx.y;
  int by = blockIdx.x >> 3, bx = blockIdx.x & 7;
  int y0 = by * 16, x0 = bx * 16;
  int h0 = 4 * y0 - 2, w0 = 4 * x0 - 2;
  float2 mi = muinv[b];
  const float* Sb = S + (size_t)b * 262144;
  for (int idx = threadIdx.x; idx < 67 * 67; idx += 256) {
    int wl = idx / 67, hl = idx - wl * 67;
    int hh = h0 + hl, ww = w0 + wl;
    float val = 0.0f;
    if (hh >= 0 && hh < 512 && ww >= 0 && ww < 512)
      val = (Sb[(size_t)ww * 512 + hh] - mi.x) * mi.y;
    tile[wl * TS1 + hl] = val;
  }
  __syncthreads();
  int ty = threadIdx.x >> 4, tx = threadIdx.x & 15;
  float in[7][7];
#pragma unroll
  for (int j = 0; j < 7; ++j)
#pragma unroll
    for (int i = 0; i < 7; ++i)
      in[i][j] = tile[(4 * tx + j) * TS1 + 4 * ty + i];
  int Y = y0 + ty, X = x0 + tx;
  for (int occ = 0; occ < 8; ++occ) {
    float w4[4][25];
#pragma unroll
    for (int jo = 0; jo < 4; ++jo)
#pragma unroll
      for (int k = 0; k < 25; ++k)
        w4[jo][k] = w[(occ * 4 + jo) * 25 + k];
#pragma unroll
    for (int jo = 0; jo < 4; ++jo) {
      int oc = occ * 4 + jo;
      float a00 = 0.f, a01 = 0.f, a10 = 0.f, a11 = 0.f;
#pragma unroll
      for (int dy = 0; dy < 5; ++dy)
#pragma unroll
        for (int dx = 0; dx < 5; ++dx) {
          float wv = w4[jo][dy * 5 + dx];
          a00 = fmaf(wv, in[dy][dx], a00);
          a01 = fmaf(wv, in[dy][dx + 2], a01);
          a10 = fmaf(wv, in[dy + 2][dx], a10);
          a11 = fmaf(wv, in[dy + 2][dx + 2], a11);
        }
      float m   = fmaxf(fmaxf(a00, a01), fmaxf(a10, a11));
      float inv = g[oc] / sqrtf(bv[oc] + 1e-5f);
      float sh  = cb[oc] * inv + bb[oc] - bm[oc] * inv;
      h1[(((size_t)b * 32 + oc) * 128 + Y) * 128 + X] = fmaxf(m * inv + sh, 0.0f);
    }
  }
}

// ------------------------------------------------- K5: conv2(3x3,s2,p1,32->64) + BN + ReLU + maxpool2
// v6: T14 async-STAGE (8 waves x 8 oc) + packed v_pk_fma_f32 inner loop.
#define TS2 36
__global__ __launch_bounds__(512) void k_conv2(
    const float* __restrict__ h1, const float* __restrict__ w,
    const float* __restrict__ cb, const float* __restrict__ g,
    const float* __restrict__ bb, const float* __restrict__ bm,
    const float* __restrict__ bv, float* __restrict__ h2) {
  __shared__ __attribute__((aligned(16))) float tile[8 * 33 * TS2];  // 38016 B
  int tid = threadIdx.x;
  int b = blockIdx.y;
  int rt = blockIdx.x >> 2, ct = blockIdx.x & 3;
  int ty0 = rt * 16, tx0 = ct * 16;                     // conv-tile origin (16x16 conv)
  int wv = tid >> 6;                                    // wave id 0..7 -> oc subgroup (8 oc)
  int lane = tid & 63;
  int qy = lane >> 3, qx = lane & 7;                    // 8x8 quads = 8x8 pooled outputs
  int iy0 = 2 * ty0 - 1, ix0 = 2 * tx0 - 1;
  int ocbase = wv * 8;
  f2 accA[8], accB[8];
#pragma unroll
  for (int q = 0; q < 8; ++q) {
    accA[q] = (f2){0.0f, 0.0f};
    accB[q] = (f2){0.0f, 0.0f};
  }

  float rv[18];
  const size_t hb = (size_t)b * 32;

  // ---- staging helpers: 8712 = 512*17 + 8 elements per ic-tile ----
#define C2_LOADR(ICT)                                                          \
  {                                                                            \
    _Pragma("unroll")                                                          \
    for (int k = 0; k < 17; ++k) {                                             \
      int idx = tid + 512 * k;                                                 \
      int ic = idx / 1089;                                                     \
      int rem = idx - ic * 1089;                                               \
      int rr = rem / 33, cc = rem - rr * 33;                                   \
      int iy = iy0 + rr, ix = ix0 + cc;                                        \
      float v = 0.0f;                                                          \
      if (iy >= 0 && iy < 128 && ix >= 0 && ix < 128)                          \
        v = h1[((hb + (ICT) * 8 + ic) * 128 + iy) * 128 + ix];                 \
      rv[k] = v;                                                               \
    }                                                                          \
    if (tid < 8) {                                                             \
      int idx = 8704 + tid;                                                    \
      int ic = idx / 1089;                                                     \
      int rem = idx - ic * 1089;                                               \
      int rr = rem / 33, cc = rem - rr * 33;                                   \
      int iy = iy0 + rr, ix = ix0 + cc;                                        \
      float v = 0.0f;                                                          \
      if (iy >= 0 && iy < 128 && ix >= 0 && ix < 128)                          \
        v = h1[((hb + (ICT) * 8 + ic) * 128 + iy) * 128 + ix];                 \
      rv[17] = v;                                                              \
    }                                                                          \
  }

#define C2_WRITER()                                                            \
  {                                                                            \
    _Pragma("unroll")                                                          \
    for (int k = 0; k < 17; ++k) {                                             \
      int idx = tid + 512 * k;                                                 \
      int ic = idx / 1089;                                                     \
      int rem = idx - ic * 1089;                                               \
      int rr = rem / 33, cc = rem - rr * 33;                                   \
      tile[(ic * 33 + rr) * TS2 + cc] = rv[k];                                 \
    }                                                                          \
    if (tid < 8) {                                                             \
      int idx = 8704 + tid;                                                    \
      int ic = idx / 1089;                                                     \
      int rem = idx - ic * 1089;                                               \
      int rr = rem / 33, cc = rem - rr * 33;                                   \
      tile[(ic * 33 + rr) * TS2 + cc] = rv[17];                                \
    }                                                                          \
  }

  C2_LOADR(0);
  for (int ict = 0; ict < 4; ++ict) {
    __syncthreads();          // previous compute done reading tile
    C2_WRITER();              // (waits vmcnt for rv loads -- issued a phase ago)
    __syncthreads();
    if (ict < 3) C2_LOADR(ict + 1);   // issue next tile's loads early
    int rbase = 4 * qy, cbase = 4 * qx;
#pragma unroll
    for (int ic = 0; ic < 8; ++ic) {
      int icg = ict * 8 + ic;
      f2 P[5][3];
#pragma unroll
      for (int i = 0; i < 5; ++i) {
        int base = (ic * 33 + rbase + i) * TS2 + cbase;
        float4 a  = *reinterpret_cast<const float4*>(&tile[base]);
        float4 bq = *reinterpret_cast<const float4*>(&tile[base + 4]);
        P[i][0] = (f2){a.x, a.z};
        P[i][1] = (f2){a.y, a.w};
        P[i][2] = (f2){a.z, bq.x};
      }
      const float* wic = w + ((size_t)ocbase * 32 + icg) * 9;
#pragma unroll
      for (int q = 0; q < 8; ++q) {
        const float* wo = wic + (size_t)q * 32 * 9;
#pragma unroll
        for (int dy = 0; dy < 3; ++dy)
#pragma unroll
          for (int dx = 0; dx < 3; ++dx) {
            float wvv = wo[dy * 3 + dx];
            f2 wv2 = (f2){wvv, wvv};
            accA[q] = __builtin_elementwise_fma(wv2, P[dy][dx],     accA[q]);
            accB[q] = __builtin_elementwise_fma(wv2, P[dy + 2][dx], accB[q]);
          }
      }
    }
  }
  int Yp = (ty0 >> 1) + qy, Xp = (tx0 >> 1) + qx;
#pragma unroll
  for (int q = 0; q < 8; ++q) {
    int oc = ocbase + q;
    float m   = fmaxf(fmaxf(accA[q].x, accA[q].y), fmaxf(accB[q].x, accB[q].y));
    float inv = g[oc] / sqrtf(bv[oc] + 1e-5f);
    float sh  = cb[oc] * inv + bb[oc] - bm[oc] * inv;
    h2[(((size_t)b * 64 + oc) * 32 + Yp) * 32 + Xp] = fmaxf(m * inv + sh, 0.0f);
  }
#undef C2_LOADR
#undef C2_WRITER
}

// ------------------------------------------------- K6: conv3(3x3,s2,p1,64->128) + BN + ReLU + GAP
#define TS3 34
__global__ __launch_bounds__(256) void k_conv3(
    const float* __restrict__ h2, const float* __restrict__ w,
    const float* __restrict__ cb, const float* __restrict__ g,
    const float* __restrict__ bb, const float* __restrict__ bm,
    const float* __restrict__ bv, float* __restrict__ gap) {
  __shared__ __attribute__((aligned(16))) float tile[8 * 33 * TS3];
  __shared__ float ws3[8][4];
  int tid = threadIdx.x;
  int ocg = blockIdx.x, b = blockIdx.y;
  int cy = tid >> 4, cx = tid & 15;
  float acc[8];
#pragma unroll
  for (int q = 0; q < 8; ++q) acc[q] = 0.0f;

  for (int ict = 0; ict < 8; ++ict) {
    __syncthreads();
    for (int idx = tid; idx < 8 * 33 * 33; idx += 256) {
      int ic = idx / 1089;
      int rem = idx - ic * 1089;
      int rr = rem / 33, cc = rem - rr * 33;
      int iy = rr - 1, ix = cc - 1;
      float v = 0.0f;
      int icg = ict * 8 + ic;
      if (iy >= 0 && iy < 32 && ix >= 0 && ix < 32)
        v = h2[(((size_t)b * 64 + icg) * 32 + iy) * 32 + ix];
      tile[(ic * 33 + rr) * TS3 + cc] = v;
    }
    __syncthreads();
#pragma unroll
    for (int ic = 0; ic < 8; ++ic) {
      int icg = ict * 8 + ic;
      float in[3][3];
#pragma unroll
      for (int i = 0; i < 3; ++i) {
        const float2* r2 = reinterpret_cast<const float2*>(&tile[(ic * 33 + 2 * cy + i) * TS3 + 2 * cx]);
        float2 a = r2[0];
        in[i][0] = a.x; in[i][1] = a.y;
        in[i][2] = tile[(ic * 33 + 2 * cy + i) * TS3 + 2 * cx + 2];
      }
      const float* wic = w + ((size_t)(ocg * 8) * 64 + icg) * 9;
#pragma unroll
      for (int q = 0; q < 8; ++q) {
        const float* wo = wic + (size_t)q * 64 * 9;
#pragma unroll
        for (int i = 0; i < 3; ++i)
#pragma unroll
          for (int j = 0; j < 3; ++j)
            acc[q] = fmaf(wo[i * 3 + j], in[i][j], acc[q]);
      }
    }
  }
  // GAP epilogue: wave shuffle reduce per oc, one barrier total
  int wvid = tid >> 6;
#pragma unroll
  for (int q = 0; q < 8; ++q) {
    int oc = ocg * 8 + q;
    float inv = g[oc] / sqrtf(bv[oc] + 1e-5f);
    float sh  = cb[oc] * inv + bb[oc] - bm[oc] * inv;
    float v = fmaxf(acc[q] * inv + sh, 0.0f);
#pragma unroll
    for (int off = 32; off > 0; off >>= 1) v += __shfl_down(v, off);
    if ((tid & 63) == 0) ws3[q][wvid] = v;
  }
  __syncthreads();
  if (tid < 8)
    gap[(size_t)b * 128 + ocg * 8 + tid] =
        (ws3[tid][0] + ws3[tid][1] + ws3[tid][2] + ws3[tid][3]) * (1.0f / 256.0f);
}

// ------------------------------------------------- K7: FC1+ReLU+FC2+ReLU
__global__ __launch_bounds__(256) void k_fc(
    const float* __restrict__ gap,
    const float* __restrict__ w1, const float* __restrict__ b1,
    const float* __restrict__ w2, const float* __restrict__ b2,
    float* __restrict__ out) {
  __shared__ float gv[128], hv[256];
  int b = blockIdx.x, t = threadIdx.x;
  if (t < 128) gv[t] = gap[(size_t)b * 128 + t];
  __syncthreads();
  float a1 = b1[t];
  const float* wr = w1 + (size_t)t * 128;
  for (int k = 0; k < 128; ++k) a1 = fmaf(wr[k], gv[k], a1);
  hv[t] = fmaxf(a1, 0.0f);
  __syncthreads();
  if (t < 128) {
    float a2 = b2[t];
    const float* wr2 = w2 + (size_t)t * 256;
    for (int k = 0; k < 256; ++k) a2 = fmaf(wr2[k], hv[k], a2);
    out[(size_t)b * 128 + t] = fmaxf(a2, 0.0f);
  }
}

// ================================================================ launch
extern "C" void kernel_launch(void* const* d_in, const int* in_sizes, int n_in,
                              void* d_out, int out_size, void* d_ws, size_t ws_size,
                              hipStream_t stream) {
  (void)in_sizes; (void)n_in; (void)out_size; (void)ws_size;
  const float* x   = (const float*)d_in[0];
  const float* c1w = (const float*)d_in[1];
  const float* c1b = (const float*)d_in[2];
  const float* b1g = (const float*)d_in[3];
  const float* b1b = (const float*)d_in[4];
  const float* b1m = (const float*)d_in[5];
  const float* b1v = (const float*)d_in[6];
  const float* c2w = (const float*)d_in[7];
  const float* c2b = (const float*)d_in[8];
  const float* b2g = (const float*)d_in[9];
  const float* b2b = (const float*)d_in[10];
  const float* b2m = (const float*)d_in[11];
  const float* b2v = (const float*)d_in[12];
  const float* c3w = (const float*)d_in[13];
  const float* c3b = (const float*)d_in[14];
  const float* b3g = (const float*)d_in[15];
  const float* b3b = (const float*)d_in[16];
  const float* b3m = (const float*)d_in[17];
  const float* b3v = (const float*)d_in[18];
  const float* f1w = (const float*)d_in[19];
  const float* f1b = (const float*)d_in[20];
  const float* f2w = (const float*)d_in[21];
  const float* f2b = (const float*)d_in[22];
  float* out = (float*)d_out;

  char* ws = (char*)d_ws;
  float2* G     = (float2*)(ws + 0);
  float2* GT    = (float2*)(ws + 67633152ull);
  float*  S     = (float*) (ws + 135266304ull);
  double* stats = (double*)(ws + 202375168ull);
  float2* muinv = (float2*)(ws + 202376192ull);
  float*  gap   = (float*) (ws + 202376704ull);
  float*  h1    = (float*) (ws + 0);
  float*  h2    = (float*) (ws + 135266304ull);

  k_zero_stats<<<1, 128, 0, stream>>>(stats);
  k_rowfft   <<<dim3(256, 64), 256, 0, stream>>>(x, G);
  k_transpose<<<dim3(9, 16, 64), dim3(32, 8), 0, stream>>>(G, GT);
  k_colfft   <<<dim3(257, 64), 256, 0, stream>>>(GT, S, stats);
  k_stats    <<<1, 64, 0, stream>>>(stats, muinv);
  k_conv1    <<<dim3(64, 64), 256, 0, stream>>>(S, muinv, c1w, c1b, b1g, b1b, b1m, b1v, h1);
  k_conv2    <<<dim3(16, 64), 512, 0, stream>>>(h1, c2w, c2b, b2g, b2b, b2m, b2v, h2);
  k_conv3    <<<dim3(16, 64), 256, 0, stream>>>(h2, c3w, c3b, b3g, b3b, b3m, b3v, gap);
  k_fc       <<<64, 256, 0, stream>>>(gap, f1w, f1b, f2w, f2b, out);
}

// Round 8
// 936.178 us; speedup vs baseline: 1.2806x; 1.0618x over previous
//
#include <hip/hip_runtime.h>
#include <math.h>

#define PI_F 3.14159265358979323846f
#define KS 258   // padded column count of half-spectrum G (k in [0,256], stride 258)

typedef float f2 __attribute__((ext_vector_type(2)));

// ---------------------------------------------------------------- FFT core
// Two radix-2 stages fused per LDS round trip (see round-7 notes).
__device__ __forceinline__ void fft512(float* re, float* im,
                                       const float* twr, const float* twi, int t) {
  bool act = (t < 128);
  int u = t;
#pragma unroll
  for (int s = 0; s < 8; s += 2) {
    __syncthreads();
    if (act) {
      int h  = 1 << s;
      int j  = u & (h - 1);
      int a  = ((u >> s) << (s + 2)) + j;
      int i0 = a, i1 = a + h, i2 = a + 2 * h, i3 = a + 3 * h;
      float e0r = re[i0], e0i = im[i0];
      float e1r = re[i1], e1i = im[i1];
      float e2r = re[i2], e2i = im[i2];
      float e3r = re[i3], e3i = im[i3];
      int tis = j << (8 - s);
      float wsr = twr[tis], wsi = twi[tis];
      float t1r = e1r * wsr - e1i * wsi, t1i = e1r * wsi + e1i * wsr;
      float t3r = e3r * wsr - e3i * wsi, t3i = e3r * wsi + e3i * wsr;
      float b0r = e0r + t1r, b0i = e0i + t1i;
      float b1r = e0r - t1r, b1i = e0i - t1i;
      float b2r = e2r + t3r, b2i = e2i + t3i;
      float b3r = e2r - t3r, b3i = e2i - t3i;
      int ti0 = j << (7 - s);
      int ti1 = (j + h) << (7 - s);
      float w0r = twr[ti0], w0i = twi[ti0];
      float w1r = twr[ti1], w1i = twi[ti1];
      float u2r = b2r * w0r - b2i * w0i, u2i = b2r * w0i + b2i * w0r;
      float u3r = b3r * w1r - b3i * w1i, u3i = b3r * w1i + b3i * w1r;
      re[i0] = b0r + u2r; im[i0] = b0i + u2i;
      re[i2] = b0r - u2r; im[i2] = b0i - u2i;
      re[i1] = b1r + u3r; im[i1] = b1i + u3i;
      re[i3] = b1r - u3r; im[i3] = b1i - u3i;
    }
  }
  __syncthreads();
  if (act) {
#pragma unroll
    for (int k = 0; k < 2; ++k) {
      int i1 = u + k * 128;
      int i2 = i1 + 256;
      float wr = twr[i1], wi = twi[i1];
      float ur = re[i1], ui = im[i1];
      float vr = re[i2], vi = im[i2];
      float tr = vr * wr - vi * wi;
      float tq = vr * wi + vi * wr;
      re[i1] = ur + tr; im[i1] = ui + tq;
      re[i2] = ur - tr; im[i2] = ui - tq;
    }
  }
  __syncthreads();
}

__device__ __forceinline__ void init_tw(float* twr, float* twi, int t) {
  float s, c;
  sincosf(-2.0f * PI_F * (float)t * (1.0f / 512.0f), &s, &c);
  twr[t] = c; twi[t] = s;
}

// ------------------------------------------------- K1: gray + paired-row FFT (Hermitian pack)
__global__ __launch_bounds__(256) void k_rowfft(const float* __restrict__ x,
                                                float2* __restrict__ G) {
  __shared__ float re[512], im[512], twr[256], twi[256];
  int t = threadIdx.x;
  int q = blockIdx.x;
  int b = blockIdx.y;
  int r0 = 2 * q;
  const float* xb = x + ((size_t)b * 3 * 512 + r0) * 512;
  float a0 = 0.299f * xb[t]           + 0.587f * xb[262144 + t]           + 0.114f * xb[524288 + t];
  float a1 = 0.299f * xb[t + 256]     + 0.587f * xb[262144 + t + 256]     + 0.114f * xb[524288 + t + 256];
  float c0 = 0.299f * xb[512 + t]     + 0.587f * xb[262656 + t]           + 0.114f * xb[524800 + t];
  float c1 = 0.299f * xb[512 + t + 256] + 0.587f * xb[262656 + t + 256]   + 0.114f * xb[524800 + t + 256];
  int rv0 = __brev((unsigned)t) >> 23;
  int rv1 = __brev((unsigned)(t + 256)) >> 23;
  re[rv0] = a0; im[rv0] = c0;
  re[rv1] = a1; im[rv1] = c1;
  init_tw(twr, twi, t);
  fft512(re, im, twr, twi, t);
  float2* G0 = G + ((size_t)b * 512 + r0) * KS;
  float2* G1 = G0 + KS;
  for (int k = t; k <= 256; k += 256) {
    int mk = (512 - k) & 511;
    float zr = re[k], zi = im[k];
    float mr = re[mk], mi = im[mk];
    G0[k] = make_float2(0.5f * (zr + mr), 0.5f * (zi - mi));
    G1[k] = make_float2(0.5f * (zi + mi), 0.5f * (mr - zr));
  }
}

// ------------------------------------------------- K1.5: out-of-place transpose G -> GT
__global__ __launch_bounds__(256) void k_transpose(const float2* __restrict__ G,
                                                   float2* __restrict__ GT) {
  __shared__ float2 ta[32][33];
  int kt = blockIdx.x, rt = blockIdx.y, b = blockIdx.z;
  int tx = threadIdx.x, ty = threadIdx.y;
  int k0 = kt * 32, r0 = rt * 32;
  const float2* Gb = G + (size_t)b * 512 * KS;
  float2* GTb = GT + (size_t)b * KS * 512;
#pragma unroll
  for (int i = 0; i < 32; i += 8) {
    int k = k0 + tx;
    float2 v = make_float2(0.0f, 0.0f);
    if (k < KS) v = Gb[(size_t)(r0 + ty + i) * KS + k];
    ta[ty + i][tx] = v;
  }
  __syncthreads();
#pragma unroll
  for (int i = 0; i < 32; i += 8) {
    int k = k0 + ty + i;
    if (k < KS) GTb[(size_t)k * 512 + r0 + tx] = ta[tx][ty + i];
  }
}

// ------------------------------------------------- K2: column FFT + mag/log1p/fftshift + mirror + stats
__global__ __launch_bounds__(256) void k_colfft(const float2* __restrict__ GT,
                                                float* __restrict__ S,
                                                double* __restrict__ stats) {
  __shared__ float re[512], im[512], twr[256], twi[256];
  __shared__ float ws1[4], ws2[4];
  int t  = threadIdx.x;
  int kc = blockIdx.x;
  int b  = blockIdx.y;
  const float2* Gc = GT + ((size_t)b * KS + kc) * 512;
  float2 v0 = Gc[t], v1 = Gc[t + 256];
  int rv0 = __brev((unsigned)t) >> 23;
  int rv1 = __brev((unsigned)(t + 256)) >> 23;
  re[rv0] = v0.x; im[rv0] = v0.y;
  re[rv1] = v1.x; im[rv1] = v1.y;
  init_tw(twr, twi, t);
  fft512(re, im, twr, twi, t);
  float m0 = log1pf(sqrtf(re[t] * re[t] + im[t] * im[t]));
  float m1 = log1pf(sqrtf(re[t + 256] * re[t + 256] + im[t + 256] * im[t + 256]));
  int v = (kc + 256) & 511;
  float* Sb = S + (size_t)b * 262144;
  Sb[(size_t)v * 512 + t + 256] = m0;
  Sb[(size_t)v * 512 + t]       = m1;
  bool mir = (kc >= 1) && (kc <= 255);
  if (mir) {
    int vp = 256 - kc;
    Sb[(size_t)vp * 512 + ((256 - t) & 511)] = m0;
    Sb[(size_t)vp * 512 + ((512 - t) & 511)] = m1;
  }
  float s1 = m0 + m1;
  float s2 = m0 * m0 + m1 * m1;
#pragma unroll
  for (int off = 32; off > 0; off >>= 1) {
    s1 += __shfl_down(s1, off);
    s2 += __shfl_down(s2, off);
  }
  int wvid = t >> 6;
  if ((t & 63) == 0) { ws1[wvid] = s1; ws2[wvid] = s2; }
  __syncthreads();
  if (t == 0) {
    float a = ws1[0] + ws1[1] + ws1[2] + ws1[3];
    float c = ws2[0] + ws2[1] + ws2[2] + ws2[3];
    double wgt = mir ? 2.0 : 1.0;
    atomicAdd(&stats[2 * b],     wgt * (double)a);
    atomicAdd(&stats[2 * b + 1], wgt * (double)c);
  }
}

__global__ void k_zero_stats(double* stats) {
  stats[threadIdx.x] = 0.0;
}

__global__ void k_stats(const double* __restrict__ stats, float2* __restrict__ muinv) {
  int i = threadIdx.x;  // 64
  double n  = 262144.0;
  double mu = stats[2 * i] / n;
  double va = stats[2 * i + 1] / n - mu * mu;
  if (va < 0.0) va = 0.0;
  double sd = sqrt(va);
  muinv[i] = make_float2((float)mu, (float)(1.0 / (sd + 1e-8)));
}

// ------------------------------------------------- K4: conv1(5x5,s2,p2) + BN + ReLU + maxpool2
// v2: packed v_pk_fma_f32 quad (cols paired, weight splat) -- the conv2-proven
// transform. 3200 -> 1600 FMA/thread. w4[100] preload dropped for inline
// uniform s_loads (VGPR down, scalar pipe absorbs weight reads).
#define TS1 68
__global__ __launch_bounds__(256) void k_conv1(
    const float* __restrict__ S, const float2* __restrict__ muinv,
    const float* __restrict__ w, const float* __restrict__ cb,
    const float* __restrict__ g, const float* __restrict__ bb,
    const float* __restrict__ bm, const float* __restrict__ bv,
    float* __restrict__ h1) {
  __shared__ float tile[67 * TS1];
  int b = blockIdx.y;
  int by = blockIdx.x >> 3, bx = blockIdx.x & 7;
  int y0 = by * 16, x0 = bx * 16;
  int h0 = 4 * y0 - 2, w0 = 4 * x0 - 2;
  float2 mi = muinv[b];
  const float* Sb = S + (size_t)b * 262144;
  for (int idx = threadIdx.x; idx < 67 * 67; idx += 256) {
    int wl = idx / 67, hl = idx - wl * 67;
    int hh = h0 + hl, ww = w0 + wl;
    float val = 0.0f;
    if (hh >= 0 && hh < 512 && ww >= 0 && ww < 512)
      val = (Sb[(size_t)ww * 512 + hh] - mi.x) * mi.y;
    tile[wl * TS1 + hl] = val;
  }
  __syncthreads();
  int ty = threadIdx.x >> 4, tx = threadIdx.x & 15;
  float in[7][7];
#pragma unroll
  for (int j = 0; j < 7; ++j)
#pragma unroll
    for (int i = 0; i < 7; ++i)
      in[i][j] = tile[(4 * tx + j) * TS1 + 4 * ty + i];
  // packed pairs: P[r][c] = {in[r][c], in[r][c+2]}  (x-direction pair)
  f2 P[7][5];
#pragma unroll
  for (int r = 0; r < 7; ++r)
#pragma unroll
    for (int c = 0; c < 5; ++c)
      P[r][c] = (f2){in[r][c], in[r][c + 2]};
  int Y = y0 + ty, X = x0 + tx;
  for (int oc = 0; oc < 32; ++oc) {
    const float* wo = w + oc * 25;
    f2 aA = (f2){0.0f, 0.0f};   // {a00, a01}
    f2 aB = (f2){0.0f, 0.0f};   // {a10, a11}
#pragma unroll
    for (int dy = 0; dy < 5; ++dy)
#pragma unroll
      for (int dx = 0; dx < 5; ++dx) {
        float wv = wo[dy * 5 + dx];
        f2 wv2 = (f2){wv, wv};
        aA = __builtin_elementwise_fma(wv2, P[dy][dx],     aA);
        aB = __builtin_elementwise_fma(wv2, P[dy + 2][dx], aB);
      }
    float m   = fmaxf(fmaxf(aA.x, aA.y), fmaxf(aB.x, aB.y));
    float inv = g[oc] / sqrtf(bv[oc] + 1e-5f);
    float sh  = cb[oc] * inv + bb[oc] - bm[oc] * inv;
    h1[(((size_t)b * 32 + oc) * 128 + Y) * 128 + X] = fmaxf(m * inv + sh, 0.0f);
  }
}

// ------------------------------------------------- K5: conv2(3x3,s2,p1,32->64) + BN + ReLU + maxpool2
// v6: T14 async-STAGE (8 waves x 8 oc) + packed v_pk_fma_f32 inner loop.
#define TS2 36
__global__ __launch_bounds__(512) void k_conv2(
    const float* __restrict__ h1, const float* __restrict__ w,
    const float* __restrict__ cb, const float* __restrict__ g,
    const float* __restrict__ bb, const float* __restrict__ bm,
    const float* __restrict__ bv, float* __restrict__ h2) {
  __shared__ __attribute__((aligned(16))) float tile[8 * 33 * TS2];  // 38016 B
  int tid = threadIdx.x;
  int b = blockIdx.y;
  int rt = blockIdx.x >> 2, ct = blockIdx.x & 3;
  int ty0 = rt * 16, tx0 = ct * 16;                     // conv-tile origin (16x16 conv)
  int wv = tid >> 6;                                    // wave id 0..7 -> oc subgroup (8 oc)
  int lane = tid & 63;
  int qy = lane >> 3, qx = lane & 7;                    // 8x8 quads = 8x8 pooled outputs
  int iy0 = 2 * ty0 - 1, ix0 = 2 * tx0 - 1;
  int ocbase = wv * 8;
  f2 accA[8], accB[8];
#pragma unroll
  for (int q = 0; q < 8; ++q) {
    accA[q] = (f2){0.0f, 0.0f};
    accB[q] = (f2){0.0f, 0.0f};
  }

  float rv[18];
  const size_t hb = (size_t)b * 32;

#define C2_LOADR(ICT)                                                          \
  {                                                                            \
    _Pragma("unroll")                                                          \
    for (int k = 0; k < 17; ++k) {                                             \
      int idx = tid + 512 * k;                                                 \
      int ic = idx / 1089;                                                     \
      int rem = idx - ic * 1089;                                               \
      int rr = rem / 33, cc = rem - rr * 33;                                   \
      int iy = iy0 + rr, ix = ix0 + cc;                                        \
      float v = 0.0f;                                                          \
      if (iy >= 0 && iy < 128 && ix >= 0 && ix < 128)                          \
        v = h1[((hb + (ICT) * 8 + ic) * 128 + iy) * 128 + ix];                 \
      rv[k] = v;                                                               \
    }                                                                          \
    if (tid < 8) {                                                             \
      int idx = 8704 + tid;                                                    \
      int ic = idx / 1089;                                                     \
      int rem = idx - ic * 1089;                                               \
      int rr = rem / 33, cc = rem - rr * 33;                                   \
      int iy = iy0 + rr, ix = ix0 + cc;                                        \
      float v = 0.0f;                                                          \
      if (iy >= 0 && iy < 128 && ix >= 0 && ix < 128)                          \
        v = h1[((hb + (ICT) * 8 + ic) * 128 + iy) * 128 + ix];                 \
      rv[17] = v;                                                              \
    }                                                                          \
  }

#define C2_WRITER()                                                            \
  {                                                                            \
    _Pragma("unroll")                                                          \
    for (int k = 0; k < 17; ++k) {                                             \
      int idx = tid + 512 * k;                                                 \
      int ic = idx / 1089;                                                     \
      int rem = idx - ic * 1089;                                               \
      int rr = rem / 33, cc = rem - rr * 33;                                   \
      tile[(ic * 33 + rr) * TS2 + cc] = rv[k];                                 \
    }                                                                          \
    if (tid < 8) {                                                             \
      int idx = 8704 + tid;                                                    \
      int ic = idx / 1089;                                                     \
      int rem = idx - ic * 1089;                                               \
      int rr = rem / 33, cc = rem - rr * 33;                                   \
      tile[(ic * 33 + rr) * TS2 + cc] = rv[17];                                \
    }                                                                          \
  }

  C2_LOADR(0);
  for (int ict = 0; ict < 4; ++ict) {
    __syncthreads();
    C2_WRITER();
    __syncthreads();
    if (ict < 3) C2_LOADR(ict + 1);
    int rbase = 4 * qy, cbase = 4 * qx;
#pragma unroll
    for (int ic = 0; ic < 8; ++ic) {
      int icg = ict * 8 + ic;
      f2 P[5][3];
#pragma unroll
      for (int i = 0; i < 5; ++i) {
        int base = (ic * 33 + rbase + i) * TS2 + cbase;
        float4 a  = *reinterpret_cast<const float4*>(&tile[base]);
        float4 bq = *reinterpret_cast<const float4*>(&tile[base + 4]);
        P[i][0] = (f2){a.x, a.z};
        P[i][1] = (f2){a.y, a.w};
        P[i][2] = (f2){a.z, bq.x};
      }
      const float* wic = w + ((size_t)ocbase * 32 + icg) * 9;
#pragma unroll
      for (int q = 0; q < 8; ++q) {
        const float* wo = wic + (size_t)q * 32 * 9;
#pragma unroll
        for (int dy = 0; dy < 3; ++dy)
#pragma unroll
          for (int dx = 0; dx < 3; ++dx) {
            float wvv = wo[dy * 3 + dx];
            f2 wv2 = (f2){wvv, wvv};
            accA[q] = __builtin_elementwise_fma(wv2, P[dy][dx],     accA[q]);
            accB[q] = __builtin_elementwise_fma(wv2, P[dy + 2][dx], accB[q]);
          }
      }
    }
  }
  int Yp = (ty0 >> 1) + qy, Xp = (tx0 >> 1) + qx;
#pragma unroll
  for (int q = 0; q < 8; ++q) {
    int oc = ocbase + q;
    float m   = fmaxf(fmaxf(accA[q].x, accA[q].y), fmaxf(accB[q].x, accB[q].y));
    float inv = g[oc] / sqrtf(bv[oc] + 1e-5f);
    float sh  = cb[oc] * inv + bb[oc] - bm[oc] * inv;
    h2[(((size_t)b * 64 + oc) * 32 + Yp) * 32 + Xp] = fmaxf(m * inv + sh, 0.0f);
  }
#undef C2_LOADR
#undef C2_WRITER
}

// ------------------------------------------------- K6: conv3(3x3,s2,p1,64->128) + BN + ReLU + GAP
// v3: oc-paired v_pk_fma_f32 (weight pair on scalar pipe, input splat).
// 4608 -> 2304 FMA/thread. Shuffle-reduce GAP epilogue (round-7).
#define TS3 34
__global__ __launch_bounds__(256) void k_conv3(
    const float* __restrict__ h2, const float* __restrict__ w,
    const float* __restrict__ cb, const float* __restrict__ g,
    const float* __restrict__ bb, const float* __restrict__ bm,
    const float* __restrict__ bv, float* __restrict__ gap) {
  __shared__ __attribute__((aligned(16))) float tile[8 * 33 * TS3];
  __shared__ float ws3[8][4];
  int tid = threadIdx.x;
  int ocg = blockIdx.x, b = blockIdx.y;
  int cy = tid >> 4, cx = tid & 15;
  f2 accP[4];
#pragma unroll
  for (int qp = 0; qp < 4; ++qp) accP[qp] = (f2){0.0f, 0.0f};

  for (int ict = 0; ict < 8; ++ict) {
    __syncthreads();
    for (int idx = tid; idx < 8 * 33 * 33; idx += 256) {
      int ic = idx / 1089;
      int rem = idx - ic * 1089;
      int rr = rem / 33, cc = rem - rr * 33;
      int iy = rr - 1, ix = cc - 1;
      float v = 0.0f;
      int icg = ict * 8 + ic;
      if (iy >= 0 && iy < 32 && ix >= 0 && ix < 32)
        v = h2[(((size_t)b * 64 + icg) * 32 + iy) * 32 + ix];
      tile[(ic * 33 + rr) * TS3 + cc] = v;
    }
    __syncthreads();
#pragma unroll
    for (int ic = 0; ic < 8; ++ic) {
      int icg = ict * 8 + ic;
      float in[3][3];
#pragma unroll
      for (int i = 0; i < 3; ++i) {
        const float2* r2 = reinterpret_cast<const float2*>(&tile[(ic * 33 + 2 * cy + i) * TS3 + 2 * cx]);
        float2 a = r2[0];
        in[i][0] = a.x; in[i][1] = a.y;
        in[i][2] = tile[(ic * 33 + 2 * cy + i) * TS3 + 2 * cx + 2];
      }
      const float* wic = w + ((size_t)(ocg * 8) * 64 + icg) * 9;
#pragma unroll
      for (int qp = 0; qp < 4; ++qp) {
        const float* wo0 = wic + (size_t)(2 * qp) * 64 * 9;
        const float* wo1 = wo0 + 64 * 9;
#pragma unroll
        for (int i = 0; i < 3; ++i)
#pragma unroll
          for (int j = 0; j < 3; ++j) {
            f2 wp = (f2){wo0[i * 3 + j], wo1[i * 3 + j]};
            f2 iv = (f2){in[i][j], in[i][j]};
            accP[qp] = __builtin_elementwise_fma(wp, iv, accP[qp]);
          }
      }
    }
  }
  int wvid = tid >> 6;
#pragma unroll
  for (int q = 0; q < 8; ++q) {
    int oc = ocg * 8 + q;
    float a = (q & 1) ? accP[q >> 1].y : accP[q >> 1].x;
    float inv = g[oc] / sqrtf(bv[oc] + 1e-5f);
    float sh  = cb[oc] * inv + bb[oc] - bm[oc] * inv;
    float v = fmaxf(a * inv + sh, 0.0f);
#pragma unroll
    for (int off = 32; off > 0; off >>= 1) v += __shfl_down(v, off);
    if ((tid & 63) == 0) ws3[q][wvid] = v;
  }
  __syncthreads();
  if (tid < 8)
    gap[(size_t)b * 128 + ocg * 8 + tid] =
        (ws3[tid][0] + ws3[tid][1] + ws3[tid][2] + ws3[tid][3]) * (1.0f / 256.0f);
}

// ------------------------------------------------- K7: FC1+ReLU+FC2+ReLU
__global__ __launch_bounds__(256) void k_fc(
    const float* __restrict__ gap,
    const float* __restrict__ w1, const float* __restrict__ b1,
    const float* __restrict__ w2, const float* __restrict__ b2,
    float* __restrict__ out) {
  __shared__ float gv[128], hv[256];
  int b = blockIdx.x, t = threadIdx.x;
  if (t < 128) gv[t] = gap[(size_t)b * 128 + t];
  __syncthreads();
  float a1 = b1[t];
  const float* wr = w1 + (size_t)t * 128;
  for (int k = 0; k < 128; ++k) a1 = fmaf(wr[k], gv[k], a1);
  hv[t] = fmaxf(a1, 0.0f);
  __syncthreads();
  if (t < 128) {
    float a2 = b2[t];
    const float* wr2 = w2 + (size_t)t * 256;
    for (int k = 0; k < 256; ++k) a2 = fmaf(wr2[k], hv[k], a2);
    out[(size_t)b * 128 + t] = fmaxf(a2, 0.0f);
  }
}

// ================================================================ launch
extern "C" void kernel_launch(void* const* d_in, const int* in_sizes, int n_in,
                              void* d_out, int out_size, void* d_ws, size_t ws_size,
                              hipStream_t stream) {
  (void)in_sizes; (void)n_in; (void)out_size; (void)ws_size;
  const float* x   = (const float*)d_in[0];
  const float* c1w = (const float*)d_in[1];
  const float* c1b = (const float*)d_in[2];
  const float* b1g = (const float*)d_in[3];
  const float* b1b = (const float*)d_in[4];
  const float* b1m = (const float*)d_in[5];
  const float* b1v = (const float*)d_in[6];
  const float* c2w = (const float*)d_in[7];
  const float* c2b = (const float*)d_in[8];
  const float* b2g = (const float*)d_in[9];
  const float* b2b = (const float*)d_in[10];
  const float* b2m = (const float*)d_in[11];
  const float* b2v = (const float*)d_in[12];
  const float* c3w = (const float*)d_in[13];
  const float* c3b = (const float*)d_in[14];
  const float* b3g = (const float*)d_in[15];
  const float* b3b = (const float*)d_in[16];
  const float* b3m = (const float*)d_in[17];
  const float* b3v = (const float*)d_in[18];
  const float* f1w = (const float*)d_in[19];
  const float* f1b = (const float*)d_in[20];
  const float* f2w = (const float*)d_in[21];
  const float* f2b = (const float*)d_in[22];
  float* out = (float*)d_out;

  char* ws = (char*)d_ws;
  float2* G     = (float2*)(ws + 0);
  float2* GT    = (float2*)(ws + 67633152ull);
  float*  S     = (float*) (ws + 135266304ull);
  double* stats = (double*)(ws + 202375168ull);
  float2* muinv = (float2*)(ws + 202376192ull);
  float*  gap   = (float*) (ws + 202376704ull);
  float*  h1    = (float*) (ws + 0);
  float*  h2    = (float*) (ws + 135266304ull);

  k_zero_stats<<<1, 128, 0, stream>>>(stats);
  k_rowfft   <<<dim3(256, 64), 256, 0, stream>>>(x, G);
  k_transpose<<<dim3(9, 16, 64), dim3(32, 8), 0, stream>>>(G, GT);
  k_colfft   <<<dim3(257, 64), 256, 0, stream>>>(GT, S, stats);
  k_stats    <<<1, 64, 0, stream>>>(stats, muinv);
  k_conv1    <<<dim3(64, 64), 256, 0, stream>>>(S, muinv, c1w, c1b, b1g, b1b, b1m, b1v, h1);
  k_conv2    <<<dim3(16, 64), 512, 0, stream>>>(h1, c2w, c2b, b2g, b2b, b2m, b2v, h2);
  k_conv3    <<<dim3(16, 64), 256, 0, stream>>>(h2, c3w, c3b, b3g, b3b, b3m, b3v, gap);
  k_fc       <<<64, 256, 0, stream>>>(gap, f1w, f1b, f2w, f2b, out);
}

// Round 9
// 887.469 us; speedup vs baseline: 1.3509x; 1.0549x over previous
//
#include <hip/hip_runtime.h>
#include <math.h>

#define PI_F 3.14159265358979323846f
#define KS 258   // padded column count of half-spectrum G (k in [0,256], stride 258)

typedef float f2 __attribute__((ext_vector_type(2)));

// ---------------------------------------------------------------- FFT core
// Two radix-2 stages fused per LDS round trip; u in [0,128) indexes the
// butterfly group. Called with re/im pointing at a 512-float segment.
// All threads of the block must call (uniform barriers).
__device__ __forceinline__ void fft512(float* re, float* im,
                                       const float* twr, const float* twi, int u) {
#pragma unroll
  for (int s = 0; s < 8; s += 2) {
    __syncthreads();
    {
      int h  = 1 << s;
      int j  = u & (h - 1);
      int a  = ((u >> s) << (s + 2)) + j;
      int i0 = a, i1 = a + h, i2 = a + 2 * h, i3 = a + 3 * h;
      float e0r = re[i0], e0i = im[i0];
      float e1r = re[i1], e1i = im[i1];
      float e2r = re[i2], e2i = im[i2];
      float e3r = re[i3], e3i = im[i3];
      int tis = j << (8 - s);
      float wsr = twr[tis], wsi = twi[tis];
      float t1r = e1r * wsr - e1i * wsi, t1i = e1r * wsi + e1i * wsr;
      float t3r = e3r * wsr - e3i * wsi, t3i = e3r * wsi + e3i * wsr;
      float b0r = e0r + t1r, b0i = e0i + t1i;
      float b1r = e0r - t1r, b1i = e0i - t1i;
      float b2r = e2r + t3r, b2i = e2i + t3i;
      float b3r = e2r - t3r, b3i = e2i - t3i;
      int ti0 = j << (7 - s);
      int ti1 = (j + h) << (7 - s);
      float w0r = twr[ti0], w0i = twi[ti0];
      float w1r = twr[ti1], w1i = twi[ti1];
      float u2r = b2r * w0r - b2i * w0i, u2i = b2r * w0i + b2i * w0r;
      float u3r = b3r * w1r - b3i * w1i, u3i = b3r * w1i + b3i * w1r;
      re[i0] = b0r + u2r; im[i0] = b0i + u2i;
      re[i2] = b0r - u2r; im[i2] = b0i - u2i;
      re[i1] = b1r + u3r; im[i1] = b1i + u3i;
      re[i3] = b1r - u3r; im[i3] = b1i - u3i;
    }
  }
  __syncthreads();
  {
#pragma unroll
    for (int k = 0; k < 2; ++k) {
      int i1 = u + k * 128;
      int i2 = i1 + 256;
      float wr = twr[i1], wi = twi[i1];
      float ur = re[i1], ui = im[i1];
      float vr = re[i2], vi = im[i2];
      float tr = vr * wr - vi * wi;
      float tq = vr * wi + vi * wr;
      re[i1] = ur + tr; im[i1] = ui + tq;
      re[i2] = ur - tr; im[i2] = ui - tq;
    }
  }
  __syncthreads();
}

__device__ __forceinline__ void init_tw(float* twr, float* twi, int t) {
  float s, c;
  sincosf(-2.0f * PI_F * (float)t * (1.0f / 512.0f), &s, &c);
  twr[t] = c; twi[t] = s;
}

// ------------------------------------------------- K1: gray + paired-row FFT (Hermitian pack)
// v3: TWO packed FFTs per block (4 image rows). Threads split f=t>>7; each
// half (128 threads) runs a full FFT on its own LDS segment -> all 256
// threads active in every butterfly phase; block count halves.
__global__ __launch_bounds__(256) void k_rowfft(const float* __restrict__ x,
                                                float2* __restrict__ G) {
  __shared__ float re[1024], im[1024], twr[256], twi[256];
  int t = threadIdx.x;
  int q = blockIdx.x;          // 0..127
  int b = blockIdx.y;
  int f = t >> 7, u = t & 127;
  int r0 = 4 * q;
  const float* xb = x + ((size_t)b * 3 * 512 + r0) * 512;
  const float* xr = xb + (2 * f) * 512;   // row pair base for this FFT
  float* reb = re + 512 * f;
  float* imb = im + 512 * f;
#pragma unroll
  for (int j = 0; j < 4; ++j) {
    int p = u + 128 * j;
    float a = 0.299f * xr[p]        + 0.587f * xr[262144 + p]  + 0.114f * xr[524288 + p];
    float c = 0.299f * xr[512 + p]  + 0.587f * xr[262656 + p]  + 0.114f * xr[524800 + p];
    int rv = __brev((unsigned)p) >> 23;
    reb[rv] = a; imb[rv] = c;
  }
  init_tw(twr, twi, t);
  fft512(reb, imb, twr, twi, u);
  int r0p = r0 + 2 * f;
  float2* G0 = G + ((size_t)b * 512 + r0p) * KS;
  float2* G1 = G0 + KS;
  for (int k = u; k <= 256; k += 128) {
    int mk = (512 - k) & 511;
    float zr = reb[k], zi = imb[k];
    float mr = reb[mk], mi = imb[mk];
    G0[k] = make_float2(0.5f * (zr + mr), 0.5f * (zi - mi));
    G1[k] = make_float2(0.5f * (zi + mi), 0.5f * (mr - zr));
  }
}

// ------------------------------------------------- K1.5: out-of-place transpose G -> GT
__global__ __launch_bounds__(256) void k_transpose(const float2* __restrict__ G,
                                                   float2* __restrict__ GT) {
  __shared__ float2 ta[32][33];
  int kt = blockIdx.x, rt = blockIdx.y, b = blockIdx.z;
  int tx = threadIdx.x, ty = threadIdx.y;
  int k0 = kt * 32, r0 = rt * 32;
  const float2* Gb = G + (size_t)b * 512 * KS;
  float2* GTb = GT + (size_t)b * KS * 512;
#pragma unroll
  for (int i = 0; i < 32; i += 8) {
    int k = k0 + tx;
    float2 v = make_float2(0.0f, 0.0f);
    if (k < KS) v = Gb[(size_t)(r0 + ty + i) * KS + k];
    ta[ty + i][tx] = v;
  }
  __syncthreads();
#pragma unroll
  for (int i = 0; i < 32; i += 8) {
    int k = k0 + ty + i;
    if (k < KS) GTb[(size_t)k * 512 + r0 + tx] = ta[tx][ty + i];
  }
}

// ------------------------------------------------- K2: column FFT + mag/log1p/fftshift + mirror + stats
// v3: TWO columns per block (f=t>>7). Tail column kc=257 (block 128, f=1)
// is masked: its GT pad row may hold garbage/NaN -> no S writes, weight 0.
__global__ __launch_bounds__(256) void k_colfft(const float2* __restrict__ GT,
                                                float* __restrict__ S,
                                                double* __restrict__ stats) {
  __shared__ float re[1024], im[1024], twr[256], twi[256];
  __shared__ float ws1[4], ws2[4];
  int t  = threadIdx.x;
  int b  = blockIdx.y;
  int f = t >> 7, u = t & 127;
  int kc = 2 * blockIdx.x + f;
  bool valid = (kc <= 256);
  const float2* Gc = GT + ((size_t)b * KS + kc) * 512;
  float* reb = re + 512 * f;
  float* imb = im + 512 * f;
#pragma unroll
  for (int j = 0; j < 4; ++j) {
    int p = u + 128 * j;
    float2 v = Gc[p];
    int rv = __brev((unsigned)p) >> 23;
    reb[rv] = v.x; imb[rv] = v.y;
  }
  init_tw(twr, twi, t);
  fft512(reb, imb, twr, twi, u);
  int vrow = (kc + 256) & 511;
  bool mir = (kc >= 1) && (kc <= 255);
  float* Sb = S + (size_t)b * 262144;
  float s1 = 0.0f, s2 = 0.0f;
#pragma unroll
  for (int j = 0; j < 4; ++j) {
    int k = u + 128 * j;
    float mm = log1pf(sqrtf(reb[k] * reb[k] + imb[k] * imb[k]));
    if (valid) {
      Sb[(size_t)vrow * 512 + ((k + 256) & 511)] = mm;
      if (mir) Sb[(size_t)(256 - kc) * 512 + ((256 - k) & 511)] = mm;
      s1 += mm; s2 += mm * mm;
    }
  }
  float w = mir ? 2.0f : (valid ? 1.0f : 0.0f);
  s1 *= w; s2 *= w;
#pragma unroll
  for (int off = 32; off > 0; off >>= 1) {
    s1 += __shfl_down(s1, off);
    s2 += __shfl_down(s2, off);
  }
  int wvid = t >> 6;
  if ((t & 63) == 0) { ws1[wvid] = s1; ws2[wvid] = s2; }
  __syncthreads();
  if (t == 0) {
    float a = ws1[0] + ws1[1] + ws1[2] + ws1[3];
    float c = ws2[0] + ws2[1] + ws2[2] + ws2[3];
    atomicAdd(&stats[2 * b],     (double)a);
    atomicAdd(&stats[2 * b + 1], (double)c);
  }
}

__global__ void k_zero_stats(double* stats) {
  stats[threadIdx.x] = 0.0;
}

__global__ void k_stats(const double* __restrict__ stats, float2* __restrict__ muinv) {
  int i = threadIdx.x;  // 64
  double n  = 262144.0;
  double mu = stats[2 * i] / n;
  double va = stats[2 * i + 1] / n - mu * mu;
  if (va < 0.0) va = 0.0;
  double sd = sqrt(va);
  muinv[i] = make_float2((float)mu, (float)(1.0 / (sd + 1e-8)));
}

// ------------------------------------------------- K4: conv1(5x5,s2,p2) + BN + ReLU + maxpool2
// packed v_pk_fma_f32 quad (round-8 proven).
#define TS1 68
__global__ __launch_bounds__(256) void k_conv1(
    const float* __restrict__ S, const float2* __restrict__ muinv,
    const float* __restrict__ w, const float* __restrict__ cb,
    const float* __restrict__ g, const float* __restrict__ bb,
    const float* __restrict__ bm, const float* __restrict__ bv,
    float* __restrict__ h1) {
  __shared__ float tile[67 * TS1];
  int b = blockIdx.y;
  int by = blockIdx.x >> 3, bx = blockIdx.x & 7;
  int y0 = by * 16, x0 = bx * 16;
  int h0 = 4 * y0 - 2, w0 = 4 * x0 - 2;
  float2 mi = muinv[b];
  const float* Sb = S + (size_t)b * 262144;
  for (int idx = threadIdx.x; idx < 67 * 67; idx += 256) {
    int wl = idx / 67, hl = idx - wl * 67;
    int hh = h0 + hl, ww = w0 + wl;
    float val = 0.0f;
    if (hh >= 0 && hh < 512 && ww >= 0 && ww < 512)
      val = (Sb[(size_t)ww * 512 + hh] - mi.x) * mi.y;
    tile[wl * TS1 + hl] = val;
  }
  __syncthreads();
  int ty = threadIdx.x >> 4, tx = threadIdx.x & 15;
  float in[7][7];
#pragma unroll
  for (int j = 0; j < 7; ++j)
#pragma unroll
    for (int i = 0; i < 7; ++i)
      in[i][j] = tile[(4 * tx + j) * TS1 + 4 * ty + i];
  f2 P[7][5];
#pragma unroll
  for (int r = 0; r < 7; ++r)
#pragma unroll
    for (int c = 0; c < 5; ++c)
      P[r][c] = (f2){in[r][c], in[r][c + 2]};
  int Y = y0 + ty, X = x0 + tx;
  for (int oc = 0; oc < 32; ++oc) {
    const float* wo = w + oc * 25;
    f2 aA = (f2){0.0f, 0.0f};
    f2 aB = (f2){0.0f, 0.0f};
#pragma unroll
    for (int dy = 0; dy < 5; ++dy)
#pragma unroll
      for (int dx = 0; dx < 5; ++dx) {
        float wv = wo[dy * 5 + dx];
        f2 wv2 = (f2){wv, wv};
        aA = __builtin_elementwise_fma(wv2, P[dy][dx],     aA);
        aB = __builtin_elementwise_fma(wv2, P[dy + 2][dx], aB);
      }
    float m   = fmaxf(fmaxf(aA.x, aA.y), fmaxf(aB.x, aB.y));
    float inv = g[oc] / sqrtf(bv[oc] + 1e-5f);
    float sh  = cb[oc] * inv + bb[oc] - bm[oc] * inv;
    h1[(((size_t)b * 32 + oc) * 128 + Y) * 128 + X] = fmaxf(m * inv + sh, 0.0f);
  }
}

// ------------------------------------------------- K5: conv2(3x3,s2,p1,32->64) + BN + ReLU + maxpool2
// v7: v6 + single b32 for the 5th column (was a second b128 wasting 12B/16B).
#define TS2 36
__global__ __launch_bounds__(512) void k_conv2(
    const float* __restrict__ h1, const float* __restrict__ w,
    const float* __restrict__ cb, const float* __restrict__ g,
    const float* __restrict__ bb, const float* __restrict__ bm,
    const float* __restrict__ bv, float* __restrict__ h2) {
  __shared__ __attribute__((aligned(16))) float tile[8 * 33 * TS2];  // 38016 B
  int tid = threadIdx.x;
  int b = blockIdx.y;
  int rt = blockIdx.x >> 2, ct = blockIdx.x & 3;
  int ty0 = rt * 16, tx0 = ct * 16;
  int wv = tid >> 6;
  int lane = tid & 63;
  int qy = lane >> 3, qx = lane & 7;
  int iy0 = 2 * ty0 - 1, ix0 = 2 * tx0 - 1;
  int ocbase = wv * 8;
  f2 accA[8], accB[8];
#pragma unroll
  for (int q = 0; q < 8; ++q) {
    accA[q] = (f2){0.0f, 0.0f};
    accB[q] = (f2){0.0f, 0.0f};
  }

  float rv[18];
  const size_t hb = (size_t)b * 32;

#define C2_LOADR(ICT)                                                          \
  {                                                                            \
    _Pragma("unroll")                                                          \
    for (int k = 0; k < 17; ++k) {                                             \
      int idx = tid + 512 * k;                                                 \
      int ic = idx / 1089;                                                     \
      int rem = idx - ic * 1089;                                               \
      int rr = rem / 33, cc = rem - rr * 33;                                   \
      int iy = iy0 + rr, ix = ix0 + cc;                                        \
      float v = 0.0f;                                                          \
      if (iy >= 0 && iy < 128 && ix >= 0 && ix < 128)                          \
        v = h1[((hb + (ICT) * 8 + ic) * 128 + iy) * 128 + ix];                 \
      rv[k] = v;                                                               \
    }                                                                          \
    if (tid < 8) {                                                             \
      int idx = 8704 + tid;                                                    \
      int ic = idx / 1089;                                                     \
      int rem = idx - ic * 1089;                                               \
      int rr = rem / 33, cc = rem - rr * 33;                                   \
      int iy = iy0 + rr, ix = ix0 + cc;                                        \
      float v = 0.0f;                                                          \
      if (iy >= 0 && iy < 128 && ix >= 0 && ix < 128)                          \
        v = h1[((hb + (ICT) * 8 + ic) * 128 + iy) * 128 + ix];                 \
      rv[17] = v;                                                              \
    }                                                                          \
  }

#define C2_WRITER()                                                            \
  {                                                                            \
    _Pragma("unroll")                                                          \
    for (int k = 0; k < 17; ++k) {                                             \
      int idx = tid + 512 * k;                                                 \
      int ic = idx / 1089;                                                     \
      int rem = idx - ic * 1089;                                               \
      int rr = rem / 33, cc = rem - rr * 33;                                   \
      tile[(ic * 33 + rr) * TS2 + cc] = rv[k];                                 \
    }                                                                          \
    if (tid < 8) {                                                             \
      int idx = 8704 + tid;                                                    \
      int ic = idx / 1089;                                                     \
      int rem = idx - ic * 1089;                                               \
      int rr = rem / 33, cc = rem - rr * 33;                                   \
      tile[(ic * 33 + rr) * TS2 + cc] = rv[17];                                \
    }                                                                          \
  }

  C2_LOADR(0);
  for (int ict = 0; ict < 4; ++ict) {
    __syncthreads();
    C2_WRITER();
    __syncthreads();
    if (ict < 3) C2_LOADR(ict + 1);
    int rbase = 4 * qy, cbase = 4 * qx;
#pragma unroll
    for (int ic = 0; ic < 8; ++ic) {
      int icg = ict * 8 + ic;
      f2 P[5][3];
#pragma unroll
      for (int i = 0; i < 5; ++i) {
        int base = (ic * 33 + rbase + i) * TS2 + cbase;
        float4 a = *reinterpret_cast<const float4*>(&tile[base]);
        float b4 = tile[base + 4];
        P[i][0] = (f2){a.x, a.z};
        P[i][1] = (f2){a.y, a.w};
        P[i][2] = (f2){a.z, b4};
      }
      const float* wic = w + ((size_t)ocbase * 32 + icg) * 9;
#pragma unroll
      for (int q = 0; q < 8; ++q) {
        const float* wo = wic + (size_t)q * 32 * 9;
#pragma unroll
        for (int dy = 0; dy < 3; ++dy)
#pragma unroll
          for (int dx = 0; dx < 3; ++dx) {
            float wvv = wo[dy * 3 + dx];
            f2 wv2 = (f2){wvv, wvv};
            accA[q] = __builtin_elementwise_fma(wv2, P[dy][dx],     accA[q]);
            accB[q] = __builtin_elementwise_fma(wv2, P[dy + 2][dx], accB[q]);
          }
      }
    }
  }
  int Yp = (ty0 >> 1) + qy, Xp = (tx0 >> 1) + qx;
#pragma unroll
  for (int q = 0; q < 8; ++q) {
    int oc = ocbase + q;
    float m   = fmaxf(fmaxf(accA[q].x, accA[q].y), fmaxf(accB[q].x, accB[q].y));
    float inv = g[oc] / sqrtf(bv[oc] + 1e-5f);
    float sh  = cb[oc] * inv + bb[oc] - bm[oc] * inv;
    h2[(((size_t)b * 64 + oc) * 32 + Yp) * 32 + Xp] = fmaxf(m * inv + sh, 0.0f);
  }
#undef C2_LOADR
#undef C2_WRITER
}

// ------------------------------------------------- K6: conv3(3x3,s2,p1,64->128) + BN + ReLU + GAP
#define TS3 34
__global__ __launch_bounds__(256) void k_conv3(
    const float* __restrict__ h2, const float* __restrict__ w,
    const float* __restrict__ cb, const float* __restrict__ g,
    const float* __restrict__ bb, const float* __restrict__ bm,
    const float* __restrict__ bv, float* __restrict__ gap) {
  __shared__ __attribute__((aligned(16))) float tile[8 * 33 * TS3];
  __shared__ float ws3[8][4];
  int tid = threadIdx.x;
  int ocg = blockIdx.x, b = blockIdx.y;
  int cy = tid >> 4, cx = tid & 15;
  f2 accP[4];
#pragma unroll
  for (int qp = 0; qp < 4; ++qp) accP[qp] = (f2){0.0f, 0.0f};

  for (int ict = 0; ict < 8; ++ict) {
    __syncthreads();
    for (int idx = tid; idx < 8 * 33 * 33; idx += 256) {
      int ic = idx / 1089;
      int rem = idx - ic * 1089;
      int rr = rem / 33, cc = rem - rr * 33;
      int iy = rr - 1, ix = cc - 1;
      float v = 0.0f;
      int icg = ict * 8 + ic;
      if (iy >= 0 && iy < 32 && ix >= 0 && ix < 32)
        v = h2[(((size_t)b * 64 + icg) * 32 + iy) * 32 + ix];
      tile[(ic * 33 + rr) * TS3 + cc] = v;
    }
    __syncthreads();
#pragma unroll
    for (int ic = 0; ic < 8; ++ic) {
      int icg = ict * 8 + ic;
      float in[3][3];
#pragma unroll
      for (int i = 0; i < 3; ++i) {
        const float2* r2 = reinterpret_cast<const float2*>(&tile[(ic * 33 + 2 * cy + i) * TS3 + 2 * cx]);
        float2 a = r2[0];
        in[i][0] = a.x; in[i][1] = a.y;
        in[i][2] = tile[(ic * 33 + 2 * cy + i) * TS3 + 2 * cx + 2];
      }
      const float* wic = w + ((size_t)(ocg * 8) * 64 + icg) * 9;
#pragma unroll
      for (int qp = 0; qp < 4; ++qp) {
        const float* wo0 = wic + (size_t)(2 * qp) * 64 * 9;
        const float* wo1 = wo0 + 64 * 9;
#pragma unroll
        for (int i = 0; i < 3; ++i)
#pragma unroll
          for (int j = 0; j < 3; ++j) {
            f2 wp = (f2){wo0[i * 3 + j], wo1[i * 3 + j]};
            f2 iv = (f2){in[i][j], in[i][j]};
            accP[qp] = __builtin_elementwise_fma(wp, iv, accP[qp]);
          }
      }
    }
  }
  int wvid = tid >> 6;
#pragma unroll
  for (int q = 0; q < 8; ++q) {
    int oc = ocg * 8 + q;
    float a = (q & 1) ? accP[q >> 1].y : accP[q >> 1].x;
    float inv = g[oc] / sqrtf(bv[oc] + 1e-5f);
    float sh  = cb[oc] * inv + bb[oc] - bm[oc] * inv;
    float v = fmaxf(a * inv + sh, 0.0f);
#pragma unroll
    for (int off = 32; off > 0; off >>= 1) v += __shfl_down(v, off);
    if ((tid & 63) == 0) ws3[q][wvid] = v;
  }
  __syncthreads();
  if (tid < 8)
    gap[(size_t)b * 128 + ocg * 8 + tid] =
        (ws3[tid][0] + ws3[tid][1] + ws3[tid][2] + ws3[tid][3]) * (1.0f / 256.0f);
}

// ------------------------------------------------- K7: FC1+ReLU+FC2+ReLU
__global__ __launch_bounds__(256) void k_fc(
    const float* __restrict__ gap,
    const float* __restrict__ w1, const float* __restrict__ b1,
    const float* __restrict__ w2, const float* __restrict__ b2,
    float* __restrict__ out) {
  __shared__ float gv[128], hv[256];
  int b = blockIdx.x, t = threadIdx.x;
  if (t < 128) gv[t] = gap[(size_t)b * 128 + t];
  __syncthreads();
  float a1 = b1[t];
  const float* wr = w1 + (size_t)t * 128;
  for (int k = 0; k < 128; ++k) a1 = fmaf(wr[k], gv[k], a1);
  hv[t] = fmaxf(a1, 0.0f);
  __syncthreads();
  if (t < 128) {
    float a2 = b2[t];
    const float* wr2 = w2 + (size_t)t * 256;
    for (int k = 0; k < 256; ++k) a2 = fmaf(wr2[k], hv[k], a2);
    out[(size_t)b * 128 + t] = fmaxf(a2, 0.0f);
  }
}

// ================================================================ launch
extern "C" void kernel_launch(void* const* d_in, const int* in_sizes, int n_in,
                              void* d_out, int out_size, void* d_ws, size_t ws_size,
                              hipStream_t stream) {
  (void)in_sizes; (void)n_in; (void)out_size; (void)ws_size;
  const float* x   = (const float*)d_in[0];
  const float* c1w = (const float*)d_in[1];
  const float* c1b = (const float*)d_in[2];
  const float* b1g = (const float*)d_in[3];
  const float* b1b = (const float*)d_in[4];
  const float* b1m = (const float*)d_in[5];
  const float* b1v = (const float*)d_in[6];
  const float* c2w = (const float*)d_in[7];
  const float* c2b = (const float*)d_in[8];
  const float* b2g = (const float*)d_in[9];
  const float* b2b = (const float*)d_in[10];
  const float* b2m = (const float*)d_in[11];
  const float* b2v = (const float*)d_in[12];
  const float* c3w = (const float*)d_in[13];
  const float* c3b = (const float*)d_in[14];
  const float* b3g = (const float*)d_in[15];
  const float* b3b = (const float*)d_in[16];
  const float* b3m = (const float*)d_in[17];
  const float* b3v = (const float*)d_in[18];
  const float* f1w = (const float*)d_in[19];
  const float* f1b = (const float*)d_in[20];
  const float* f2w = (const float*)d_in[21];
  const float* f2b = (const float*)d_in[22];
  float* out = (float*)d_out;

  char* ws = (char*)d_ws;
  float2* G     = (float2*)(ws + 0);
  float2* GT    = (float2*)(ws + 67633152ull);
  float*  S     = (float*) (ws + 135266304ull);
  double* stats = (double*)(ws + 202375168ull);
  float2* muinv = (float2*)(ws + 202376192ull);
  float*  gap   = (float*) (ws + 202376704ull);
  float*  h1    = (float*) (ws + 0);
  float*  h2    = (float*) (ws + 135266304ull);

  k_zero_stats<<<1, 128, 0, stream>>>(stats);
  k_rowfft   <<<dim3(128, 64), 256, 0, stream>>>(x, G);
  k_transpose<<<dim3(9, 16, 64), dim3(32, 8), 0, stream>>>(G, GT);
  k_colfft   <<<dim3(129, 64), 256, 0, stream>>>(GT, S, stats);
  k_stats    <<<1, 64, 0, stream>>>(stats, muinv);
  k_conv1    <<<dim3(64, 64), 256, 0, stream>>>(S, muinv, c1w, c1b, b1g, b1b, b1m, b1v, h1);
  k_conv2    <<<dim3(16, 64), 512, 0, stream>>>(h1, c2w, c2b, b2g, b2b, b2m, b2v, h2);
  k_conv3    <<<dim3(16, 64), 256, 0, stream>>>(h2, c3w, c3b, b3g, b3b, b3m, b3v, gap);
  k_fc       <<<64, 256, 0, stream>>>(gap, f1w, f1b, f2w, f2b, out);
}